// Round 3
// baseline (16926.692 us; speedup 1.0000x reference)
//
#include <hip/hip_runtime.h>

#define TILE 128
#define BKK  16

// ---------------------------------------------------------------------------
// Tiled fp32 GEMM: C[M,N] (+)= A[M,K] * B[K,N]. Row-major; explicit ldc.
// blockIdx.z: B += z*sB, C += z*sC. M%128==0, K%16==0, N%8==0.
// ---------------------------------------------------------------------------
__global__ __launch_bounds__(256) void gemm_f32(
    const float* __restrict__ A, const float* __restrict__ Bg, float* __restrict__ Cg,
    int M, int K, int N, int ldc, long long sB, long long sC, int accum)
{
    const float* B = Bg + (size_t)blockIdx.z * sB;
    float*       C = Cg + (size_t)blockIdx.z * sC;

    __shared__ float As[BKK][TILE];
    __shared__ float Bs[BKK][TILE];

    const int tid  = threadIdx.x;
    const int tx   = tid & 15;
    const int ty   = tid >> 4;
    const int row0 = blockIdx.y * TILE;
    const int col0 = blockIdx.x * TILE;

    const int ra = tid >> 2;
    const int ka = (tid & 3) << 2;
    const int kb = tid >> 4;
    const int cb = (tid & 15) << 3;

    float acc[8][8];
#pragma unroll
    for (int i = 0; i < 8; ++i)
#pragma unroll
        for (int j = 0; j < 8; ++j) acc[i][j] = 0.f;

    for (int k0 = 0; k0 < K; k0 += BKK) {
        const float4 a0 = *(const float4*)(A + (size_t)(row0 + ra)      * K + k0 + ka);
        const float4 a1 = *(const float4*)(A + (size_t)(row0 + ra + 64) * K + k0 + ka);
        float4 b0 = make_float4(0.f, 0.f, 0.f, 0.f);
        float4 b1 = make_float4(0.f, 0.f, 0.f, 0.f);
        const int cbase = col0 + cb;
        if (cbase < N)     b0 = *(const float4*)(B + (size_t)(k0 + kb) * N + cbase);
        if (cbase + 4 < N) b1 = *(const float4*)(B + (size_t)(k0 + kb) * N + cbase + 4);

        __syncthreads();
        As[ka + 0][ra] = a0.x; As[ka + 1][ra] = a0.y; As[ka + 2][ra] = a0.z; As[ka + 3][ra] = a0.w;
        As[ka + 0][ra + 64] = a1.x; As[ka + 1][ra + 64] = a1.y; As[ka + 2][ra + 64] = a1.z; As[ka + 3][ra + 64] = a1.w;
        *(float4*)&Bs[kb][cb]     = b0;
        *(float4*)&Bs[kb][cb + 4] = b1;
        __syncthreads();

#pragma unroll
        for (int kk = 0; kk < BKK; ++kk) {
            const float4 av0 = *(const float4*)(&As[kk][(ty << 2)]);
            const float4 av1 = *(const float4*)(&As[kk][(ty << 2) + 64]);
            const float4 bv0 = *(const float4*)(&Bs[kk][(tx << 2)]);
            const float4 bv1 = *(const float4*)(&Bs[kk][(tx << 2) + 64]);
            const float ar[8] = {av0.x, av0.y, av0.z, av0.w, av1.x, av1.y, av1.z, av1.w};
            const float br[8] = {bv0.x, bv0.y, bv0.z, bv0.w, bv1.x, bv1.y, bv1.z, bv1.w};
#pragma unroll
            for (int i = 0; i < 8; ++i)
#pragma unroll
                for (int j = 0; j < 8; ++j)
                    acc[i][j] = fmaf(ar[i], br[j], acc[i][j]);
        }
    }

#pragma unroll
    for (int i = 0; i < 8; ++i) {
        const int r = row0 + (ty << 2) + (i & 3) + ((i >> 2) << 6);
#pragma unroll
        for (int jh = 0; jh < 2; ++jh) {
            const int c = col0 + (tx << 2) + (jh << 6);
            if (c < N) {
                float* p = C + (size_t)r * ldc + c;
                float4 v;
                v.x = acc[i][jh * 4 + 0]; v.y = acc[i][jh * 4 + 1];
                v.z = acc[i][jh * 4 + 2]; v.w = acc[i][jh * 4 + 3];
                if (accum) {
                    const float4 o = *(const float4*)p;
                    v.x += o.x; v.y += o.y; v.z += o.z; v.w += o.w;
                }
                *(float4*)p = v;
            }
        }
    }
}

// ---------------------------------------------------------------------------
// fp64 GEMM (for the pool-argmax-critical path). TILE 64, BK 16, 256 thr,
// 4x4 micro-tile. A may be fp32 (converted on load) or fp64. M%64, K%16, N%4.
// ---------------------------------------------------------------------------
__device__ inline void loadA4(const float* p, double* d) {
    float4 v = *(const float4*)p;
    d[0] = v.x; d[1] = v.y; d[2] = v.z; d[3] = v.w;
}
__device__ inline void loadA4(const double* p, double* d) {
    double2 v0 = *(const double2*)p, v1 = *(const double2*)(p + 2);
    d[0] = v0.x; d[1] = v0.y; d[2] = v1.x; d[3] = v1.y;
}

template <typename TA>
__global__ __launch_bounds__(256) void gemm_f64(
    const TA* __restrict__ A, const double* __restrict__ B, double* __restrict__ C,
    int M, int K, int N, int accum)
{
    __shared__ double As[16][64];   // k-major
    __shared__ double Bs[16][64];

    const int tid  = threadIdx.x;
    const int tx   = tid & 15;
    const int ty   = tid >> 4;
    const int row0 = blockIdx.y * 64;
    const int col0 = blockIdx.x * 64;

    const int ra = tid >> 2;          // 0..63
    const int ka = (tid & 3) << 2;    // 0,4,8,12
    const int kb = tid >> 4;          // 0..15
    const int cb = (tid & 15) << 2;   // 0..60

    double acc[4][4];
#pragma unroll
    for (int i = 0; i < 4; ++i)
#pragma unroll
        for (int j = 0; j < 4; ++j) acc[i][j] = 0.0;

    for (int k0 = 0; k0 < K; k0 += 16) {
        double av[4];
        loadA4(A + (size_t)(row0 + ra) * K + k0 + ka, av);
        double2 b0 = {0.0, 0.0}, b1 = {0.0, 0.0};
        const int cbase = col0 + cb;
        if (cbase < N) {
            b0 = *(const double2*)(B + (size_t)(k0 + kb) * N + cbase);
            b1 = *(const double2*)(B + (size_t)(k0 + kb) * N + cbase + 2);
        }
        __syncthreads();
        As[ka + 0][ra] = av[0]; As[ka + 1][ra] = av[1];
        As[ka + 2][ra] = av[2]; As[ka + 3][ra] = av[3];
        *(double2*)&Bs[kb][cb]     = b0;
        *(double2*)&Bs[kb][cb + 2] = b1;
        __syncthreads();

#pragma unroll
        for (int kk = 0; kk < 16; ++kk) {
            double ar[4], br[4];
            ar[0] = As[kk][(ty << 2) + 0]; ar[1] = As[kk][(ty << 2) + 1];
            ar[2] = As[kk][(ty << 2) + 2]; ar[3] = As[kk][(ty << 2) + 3];
            br[0] = Bs[kk][(tx << 2) + 0]; br[1] = Bs[kk][(tx << 2) + 1];
            br[2] = Bs[kk][(tx << 2) + 2]; br[3] = Bs[kk][(tx << 2) + 3];
#pragma unroll
            for (int i = 0; i < 4; ++i)
#pragma unroll
                for (int j = 0; j < 4; ++j)
                    acc[i][j] = fma(ar[i], br[j], acc[i][j]);
        }
    }

#pragma unroll
    for (int i = 0; i < 4; ++i) {
        const int r = row0 + (ty << 2) + i;
#pragma unroll
        for (int j = 0; j < 4; ++j) {
            const int c = col0 + (tx << 2) + j;
            if (c < N) {
                double* p = C + (size_t)r * N + c;
                double v = acc[i][j];
                if (accum) v += *p;
                *p = v;
            }
        }
    }
}

// ---------------------------------------------------------------------------
// Aux kernels. Activation layout: [g=4][node][b=8][C].
// ---------------------------------------------------------------------------
__global__ void zero_k(float* __restrict__ p, int n) {
    int i = blockIdx.x * blockDim.x + threadIdx.x;
    if (i < n) p[i] = 0.f;
}

// x [32][3072][32] (fp32) -> XT64 [g][n][bi][32] (fp64)
__global__ void regroup_in64_k(const float* __restrict__ x, double* __restrict__ XT, int total) {
    int i = blockIdx.x * blockDim.x + threadIdx.x;
    if (i >= total) return;
    int c = i & 31;
    int t = i >> 5;
    int n = t % 3072;
    int b = t / 3072;
    XT[((((size_t)(b >> 3) * 3072 + n) << 3) + (b & 7)) * 32 + c] = (double)x[i];
}

// fp32 combine
__global__ void cheb_combine_k(const float* __restrict__ w, float* __restrict__ wa,
                               float* __restrict__ wb, float* __restrict__ wc, int n) {
    int i = blockIdx.x * blockDim.x + threadIdx.x;
    if (i >= n) return;
    float w0 = w[i], w1 = w[n + i], w2 = w[2 * n + i];
    wa[i] = w0 - w2; wb[i] = w1; wc[i] = 2.f * w2;
}
// fp64 combine
__global__ void cheb_combine64_k(const float* __restrict__ w, double* __restrict__ wa,
                                 double* __restrict__ wb, double* __restrict__ wc, int n) {
    int i = blockIdx.x * blockDim.x + threadIdx.x;
    if (i >= n) return;
    double w0 = w[i], w1 = w[n + i], w2 = w[2 * n + i];
    wa[i] = w0 - w2; wb[i] = w1; wc[i] = 2.0 * w2;
}

__global__ void transpose_w_k(const float* __restrict__ w, float* __restrict__ wt, int R, int Ccol) {
    int i = blockIdx.x * blockDim.x + threadIdx.x;
    if (i >= R * Ccol) return;
    int r = i / Ccol, c = i - r * Ccol;
    wt[(size_t)c * R + r] = w[i];
}
__global__ void transpose_w64_k(const float* __restrict__ w, double* __restrict__ wt, int R, int Ccol) {
    int i = blockIdx.x * blockDim.x + threadIdx.x;
    if (i >= R * Ccol) return;
    int r = i / Ccol, c = i - r * Ccol;
    wt[(size_t)c * R + r] = (double)w[i];
}

// fp32 BN
__global__ void bn_reduce_k(const float* __restrict__ X, float* __restrict__ stats,
                            int rows, int ld, int off) {
    int c = threadIdx.x;
    float s = 0.f, s2 = 0.f;
    for (int r = blockIdx.x; r < rows; r += gridDim.x) {
        float v = X[(size_t)r * ld + off + c];
        s += v; s2 += v * v;
    }
    atomicAdd(&stats[c], s);
    atomicAdd(&stats[256 + c], s2);
}
__global__ void bn_apply_k(float* X, const float* __restrict__ stats,
                           const float* __restrict__ g, const float* __restrict__ be,
                           const float* rbias, int total, int C, float invN, int ld, int off) {
    int i = blockIdx.x * blockDim.x + threadIdx.x;
    if (i >= total) return;
    int c = i % C;
    int row = i / C;
    size_t a = (size_t)row * ld + off + c;
    float mu = stats[c] * invN;
    float var = stats[256 + c] * invN - mu * mu;
    float sc = g[c] * rsqrtf(var + 1e-5f);
    float v = (X[a] - mu) * sc + be[c];
    v = fmaxf(v, 0.f);
    if (rbias) v += rbias[c];
    X[a] = v;
}

// fp64 BN
__global__ void bn_reduce64_k(const double* __restrict__ X, double* __restrict__ stats,
                              int rows, int ld) {
    int c = threadIdx.x;
    double s = 0.0, s2 = 0.0;
    for (int r = blockIdx.x; r < rows; r += gridDim.x) {
        double v = X[(size_t)r * ld + c];
        s += v; s2 += v * v;
    }
    atomicAdd(&stats[c], s);
    atomicAdd(&stats[256 + c], s2);
}
__global__ void bn_apply64_k(double* X, const double* __restrict__ stats,
                             const float* __restrict__ g, const float* __restrict__ be,
                             const float* rbias, int total, int C, double invN) {
    int i = blockIdx.x * blockDim.x + threadIdx.x;
    if (i >= total) return;
    int c = i % C;
    double mu = stats[c] * invN;
    double var = stats[256 + c] * invN - mu * mu;
    double sc = (double)g[c] / sqrt(var + 1e-5);
    double v = (X[i] - mu) * sc + (double)be[c];
    v = v > 0.0 ? v : 0.0;
    if (rbias) v += (double)rbias[c];
    X[i] = v;
}

// cast fp64 e1 [g][n][b][128] -> CAT high half (fp32, ld 256, off 128)
__global__ void cast_e1_k(const double* __restrict__ E1, float* __restrict__ cat, int total) {
    int i = blockIdx.x * blockDim.x + threadIdx.x;
    if (i >= total) return;
    int c = i & 127;
    int row = i >> 7;
    cat[(size_t)row * 256 + 128 + c] = (float)E1[i];
}

// pool 4 consecutive nodes of fp64 e1 -> P fp32 [g][q][b][128], IDX node index
__global__ void pool4_64_k(const double* __restrict__ e1, float* __restrict__ p,
                           int* __restrict__ idx, int total) {
    int i = blockIdx.x * blockDim.x + threadIdx.x;
    if (i >= total) return;
    int c = i & 127;
    int t = i >> 7;
    int b = t & 7;
    t >>= 3;
    int q = t % 768;
    int g = t / 768;
    size_t base = ((((size_t)g * 3072 + 4 * q) << 3) + b) * 128 + c;
    double best = e1[base];
    int bj = 0;
#pragma unroll
    for (int j = 1; j < 4; ++j) {
        double v = e1[base + (size_t)j * 1024];
        if (v > best) { best = v; bj = j; }   // strict >: first occurrence (jnp.argmax)
    }
    p[i] = (float)best;
    idx[i] = 4 * q + bj;
}

// scatter e2 into CAT low half
__global__ void unpool_cat_k(const float* __restrict__ e2, const int* __restrict__ idx,
                             float* __restrict__ cat, int total) {
    int i = blockIdx.x * blockDim.x + threadIdx.x;
    if (i >= total) return;
    int c = i & 127;
    int t = i >> 7;
    int b = t & 7;
    t >>= 3;
    int q = t % 768;
    int g = t / 768;
    float val = e2[i];
    int id = idx[i];
    size_t base = ((((size_t)g * 3072 + 4 * q) << 3) + b) * 256 + c;
#pragma unroll
    for (int j = 0; j < 4; ++j)
        cat[base + (size_t)j * 2048] = (4 * q + j == id) ? val : 0.f;
}

// O [g][n][bi][8] -> out [B][N][8], + bias
__global__ void transpose_out_k(const float* __restrict__ O, const float* __restrict__ bias,
                                float* __restrict__ out, int total) {
    int i = blockIdx.x * blockDim.x + threadIdx.x;
    if (i >= total) return;
    int c = i & 7;
    int t = i >> 3;
    int n = t % 3072;
    int b = t / 3072;
    out[i] = O[((((size_t)(b >> 3) * 3072 + n) << 3) + (b & 7)) * 8 + c] + bias[c];
}

// ---------------------------------------------------------------------------
extern "C" void kernel_launch(void* const* d_in, const int* in_sizes, int n_in,
                              void* d_out, int out_size, void* d_ws, size_t ws_size,
                              hipStream_t stream)
{
    (void)in_sizes; (void)n_in; (void)out_size; (void)ws_size;

    const float* x    = (const float*)d_in[0];
    const float* L0   = (const float*)d_in[1];
    const float* L1   = (const float*)d_in[2];
    const float* w11  = (const float*)d_in[3];
    const float* g11  = (const float*)d_in[5];
    const float* be11 = (const float*)d_in[6];
    const float* w13  = (const float*)d_in[7];
    const float* g13  = (const float*)d_in[9];
    const float* be13 = (const float*)d_in[10];
    const float* wr1  = (const float*)d_in[11];
    const float* br1  = (const float*)d_in[12];
    const float* w21  = (const float*)d_in[13];
    const float* g21  = (const float*)d_in[15];
    const float* be21 = (const float*)d_in[16];
    const float* w23  = (const float*)d_in[17];
    const float* g23  = (const float*)d_in[19];
    const float* be23 = (const float*)d_in[20];
    const float* wr2  = (const float*)d_in[21];
    const float* br2  = (const float*)d_in[22];
    const float* uw11 = (const float*)d_in[23];
    const float* ug11 = (const float*)d_in[25];
    const float* ube11= (const float*)d_in[26];
    const float* uw12 = (const float*)d_in[27];
    const float* ug12 = (const float*)d_in[29];
    const float* ube12= (const float*)d_in[30];
    const float* uwr1 = (const float*)d_in[31];
    const float* ubr1 = (const float*)d_in[32];
    const float* uw13 = (const float*)d_in[33];
    const float* ub13 = (const float*)d_in[34];
    float* out = (float*)d_out;

    float* ws = (float*)d_ws;
    size_t off = 0;
    auto alloc = [&](size_t n) { float* p = ws + off; off += (n + 63) & ~(size_t)63; return p; };

    // fp32 statics (~241 MB total). Order matters: D1,H64,T1f contiguous (E1_64 alias).
    float* CAT = alloc(25165824);   // [g][n][b][256]: low=u, high=e1
    float* D1  = alloc(12582912);   // d1; aliases: H2@0, Y3@+6291456, O@0
    float* H64 = alloc(6291456);    // d2
    float* T1f = alloc(6291456);
    float* T2f = alloc(6291456);
    float* P   = alloc(3145728);    // pooled [g][q][b][128]
    int*  IDX  = (int*)alloc(3145728);
    float* ST  = alloc(1536);       // fp32 stats [0..512), fp64 stats [512..1536)

    // fp32 weights (levels 2 + decoder)
    float* wa21 = alloc(24576), *wb21 = alloc(24576), *wc21 = alloc(24576);
    float* wa23 = alloc(24576), *wb23 = alloc(24576), *wc23 = alloc(24576);
    float* wau11 = alloc(32768), *wbu11 = alloc(32768), *wcu11 = alloc(32768);
    float* wau12 = alloc(8192),  *wbu12 = alloc(8192),  *wcu12 = alloc(8192);
    float* wau13 = alloc(512),   *wbu13 = alloc(512),   *wcu13 = alloc(512);
    float* wr2T  = alloc(16384);
    float* uwr1T = alloc(16384);

    // fp64 weights (encoder path)
    double* wa11_64 = (double*)alloc(4096);
    double* wb11_64 = (double*)alloc(4096);
    double* wc11_64 = (double*)alloc(4096);
    double* wa13_64 = (double*)alloc(16384);
    double* wb13_64 = (double*)alloc(16384);
    double* wc13_64 = (double*)alloc(16384);
    double* wr1T_64 = (double*)alloc(8192);

    // fp64 phase-1 buffers aliased into not-yet-live fp32 regions:
    double* XT64 = (double*)CAT;                    // [g][n][b][32]  (6.29M fl)
    double* H1   = (double*)(CAT + 6291456);        // [g][n][b][64]  (12.58M fl)
    double* T1d  = (double*)(CAT + 18874368);       // [3072][<=512]  (3.15M fl)
    double* T2d  = (double*)(CAT + 22020096);       //                (3.15M fl)
    double* E1   = (double*)D1;                     // [g][n][b][128] spans D1+H64+T1f
    double* ST64 = (double*)(ST + 512);

    // fp32 aliases (level-2 / decoder), as in R2:
    float* H2 = D1;                 // [g][q][b][192]
    float* Y3 = D1 + 6291456;       // [g][q][b][128] (e2)
    float* O  = D1;                 // final conv out [g][n][b][8]

    auto gemm = [&](const float* A, const float* B, float* C, int M, int K, int N,
                    int ldc, long long sB, long long sC, int z, int accum) {
        dim3 grid((N + TILE - 1) / TILE, M / TILE, z);
        gemm_f32<<<grid, 256, 0, stream>>>(A, B, C, M, K, N, ldc, sB, sC, accum);
    };
    auto gemm64f = [&](const float* A, const double* B, double* C, int M, int K, int N, int accum) {
        dim3 grid((N + 63) / 64, M / 64);
        gemm_f64<float><<<grid, 256, 0, stream>>>(A, B, C, M, K, N, accum);
    };
    auto gemm64d = [&](const double* A, const double* B, double* C, int M, int K, int N, int accum) {
        dim3 grid((N + 63) / 64, M / 64);
        gemm_f64<double><<<grid, 256, 0, stream>>>(A, B, C, M, K, N, accum);
    };
    auto bn = [&](float* X, int rows, int C, int ld, int offc,
                  const float* gp, const float* bep, const float* rbias) {
        zero_k<<<2, 256, 0, stream>>>(ST, 512);
        bn_reduce_k<<<384, C, 0, stream>>>(X, ST, rows, ld, offc);
        int total = rows * C;
        bn_apply_k<<<(total + 255) / 256, 256, 0, stream>>>(
            X, ST, gp, bep, rbias, total, C, 1.f / (float)rows, ld, offc);
    };
    auto bn64 = [&](double* X, int rows, int C,
                    const float* gp, const float* bep, const float* rbias) {
        zero_k<<<4, 256, 0, stream>>>(ST + 512, 1024);   // zero bits == 0.0 double
        bn_reduce64_k<<<384, C, 0, stream>>>(X, ST64, rows, C);
        int total = rows * C;
        bn_apply64_k<<<(total + 255) / 256, 256, 0, stream>>>(
            X, ST64, gp, bep, rbias, total, C, 1.0 / (double)rows);
    };
    auto comb = [&](const float* w, float* a, float* b, float* c, int n) {
        cheb_combine_k<<<(n + 255) / 256, 256, 0, stream>>>(w, a, b, c, n);
    };

    // ---- weight prep ----
    cheb_combine64_k<<<8, 256, 0, stream>>>(w11, wa11_64, wb11_64, wc11_64, 2048);
    cheb_combine64_k<<<32, 256, 0, stream>>>(w13, wa13_64, wb13_64, wc13_64, 8192);
    transpose_w64_k<<<16, 256, 0, stream>>>(wr1, wr1T_64, 128, 32);
    comb(w21,  wa21,  wb21,  wc21,  24576);
    comb(w23,  wa23,  wb23,  wc23,  24576);
    comb(uw11, wau11, wbu11, wcu11, 32768);
    comb(uw12, wau12, wbu12, wcu12, 8192);
    comb(uw13, wau13, wbu13, wcu13, 512);
    transpose_w_k<<<64, 256, 0, stream>>>(wr2, wr2T, 128, 128);
    transpose_w_k<<<64, 256, 0, stream>>>(uwr1, uwr1T, 64, 256);
    regroup_in64_k<<<12288, 256, 0, stream>>>(x, XT64, 3145728);

    // ==== PHASE 1 (fp64): encoder to e1 ====
    // conv1: 32 -> 64, per batch-group
    for (int g = 0; g < 4; ++g) {
        const double* Xg = XT64 + (size_t)g * 786432;
        double* Hg = H1 + (size_t)g * 1572864;
        gemm64f(L0, Xg, T1d, 3072, 3072, 256, 0);
        gemm64f(L0, T1d, T2d, 3072, 3072, 256, 0);
        gemm64d(Xg,  wa11_64, Hg, 24576, 32, 64, 0);
        gemm64d(T1d, wb11_64, Hg, 24576, 32, 64, 1);
        gemm64d(T2d, wc11_64, Hg, 24576, 32, 64, 1);
    }
    bn64(H1, 98304, 64, g11, be11, nullptr);                 // h1

    // conv2: 64 -> 128 (+ residual) -> E1
    for (int g = 0; g < 4; ++g) {
        const double* Hg = H1 + (size_t)g * 1572864;
        double* Eg = E1 + (size_t)g * 3145728;
        gemm64f(L0, Hg, T1d, 3072, 3072, 512, 0);
        gemm64f(L0, T1d, T2d, 3072, 3072, 512, 0);
        gemm64d(Hg,  wa13_64, Eg, 24576, 64, 128, 0);
        gemm64d(T1d, wb13_64, Eg, 24576, 64, 128, 1);
        gemm64d(T2d, wc13_64, Eg, 24576, 64, 128, 1);
    }
    bn64(E1, 98304, 128, g13, be13, br1);
    gemm64d(XT64, wr1T_64, E1, 98304, 32, 128, 1);           // e1 (fp64)

    // transition: CAT high = fp32(e1); pool on fp64 values
    cast_e1_k<<<49152, 256, 0, stream>>>(E1, CAT, 12582912);
    pool4_64_k<<<12288, 256, 0, stream>>>(E1, P, IDX, 3145728);
    // E1 / XT64 / H1 / T1d / T2d dead from here.

    // ==== PHASE 2 (fp32) ====
    // L2 conv1: 128 -> 192
    gemm(L1, P, T1f, 768, 768, 1024, 1024, 786432, 786432, 4, 0);
    gemm(L1, T1f, T2f, 768, 768, 1024, 1024, 786432, 786432, 4, 0);
    gemm(P,   wa21, H2, 24576, 128, 192, 192, 0, 0, 1, 0);
    gemm(T1f, wb21, H2, 24576, 128, 192, 192, 0, 0, 1, 1);
    gemm(T2f, wc21, H2, 24576, 128, 192, 192, 0, 0, 1, 1);
    bn(H2, 24576, 192, 192, 0, g21, be21, nullptr);          // h2

    // L2 conv2: 192 -> 128, + residual -> e2 (Y3)
    gemm(L1, H2, T1f, 768, 768, 1536, 1536, 1179648, 1179648, 4, 0);
    gemm(L1, T1f, T2f, 768, 768, 1536, 1536, 1179648, 1179648, 4, 0);
    gemm(H2,  wa23, Y3, 24576, 192, 128, 128, 0, 0, 1, 0);
    gemm(T1f, wb23, Y3, 24576, 192, 128, 128, 0, 0, 1, 1);
    gemm(T2f, wc23, Y3, 24576, 192, 128, 128, 0, 0, 1, 1);
    bn(Y3, 24576, 128, 128, 0, g23, be23, br2);
    gemm(P, wr2T, Y3, 24576, 128, 128, 128, 0, 0, 1, 1);     // e2

    // unpool into CAT low
    unpool_cat_k<<<12288, 256, 0, stream>>>(Y3, IDX, CAT, 3145728);

    // dec conv1: 256 -> 128
    for (int g = 0; g < 4; ++g) {
        const float* Bg = CAT + (size_t)g * 6291456;
        float* Dg = D1 + (size_t)g * 3145728;
        gemm(L0, Bg, T1f, 3072, 3072, 2048, 2048, 0, 0, 1, 0);
        gemm(L0, T1f, T2f, 3072, 3072, 2048, 2048, 0, 0, 1, 0);
        gemm(Bg,  wau11, Dg, 24576, 256, 128, 128, 0, 0, 1, 0);
        gemm(T1f, wbu11, Dg, 24576, 256, 128, 128, 0, 0, 1, 1);
        gemm(T2f, wcu11, Dg, 24576, 256, 128, 128, 0, 0, 1, 1);
    }
    bn(D1, 98304, 128, 128, 0, ug11, ube11, nullptr);        // d1

    // dec conv2: 128 -> 64, + residual
    for (int g = 0; g < 4; ++g) {
        const float* Bg = D1 + (size_t)g * 3145728;
        float* Dg = H64 + (size_t)g * 1572864;
        gemm(L0, Bg, T1f, 3072, 3072, 1024, 1024, 0, 0, 1, 0);
        gemm(L0, T1f, T2f, 3072, 3072, 1024, 1024, 0, 0, 1, 0);
        gemm(Bg,  wau12, Dg, 24576, 128, 64, 64, 0, 0, 1, 0);
        gemm(T1f, wbu12, Dg, 24576, 128, 64, 64, 0, 0, 1, 1);
        gemm(T2f, wcu12, Dg, 24576, 128, 64, 64, 0, 0, 1, 1);
    }
    bn(H64, 98304, 64, 64, 0, ug12, ube12, ubr1);
    gemm(CAT, uwr1T, H64, 98304, 256, 64, 64, 0, 0, 1, 1);   // d2

    // final conv: 64 -> 8
    gemm(L0, H64, T1f, 3072, 3072, 512, 512, 1572864, 1572864, 4, 0);
    gemm(L0, T1f, T2f, 3072, 3072, 512, 512, 1572864, 1572864, 4, 0);
    gemm(H64, wau13, O, 98304, 64, 8, 8, 0, 0, 1, 0);
    gemm(T1f, wbu13, O, 98304, 64, 8, 8, 0, 0, 1, 1);
    gemm(T2f, wcu13, O, 98304, 64, 8, 8, 0, 0, 1, 1);

    transpose_out_k<<<3072, 256, 0, stream>>>(O, ub13, out, 786432);
}

// Round 5
// 9209.459 us; speedup vs baseline: 1.8380x; 1.8380x over previous
//
#include <hip/hip_runtime.h>

typedef _Float16 f16;
typedef f16   half8 __attribute__((ext_vector_type(8)));
typedef float f32x4 __attribute__((ext_vector_type(4)));

#define LDH 40   // padded halves per LDS row (16B-aligned rows, conflict-reducing)

// ---------------------------------------------------------------------------
// fp16 MFMA GEMM: C[M,N] = A[M,K]*B[K,N]; A,B fp16 row-major; C per MODE.
// MODE 0: f16 store; 1: f32 store; 2: f32 accumulate-add.
// blockIdx.z batches B/C by sB/sC (element strides). M%128==0, K%32==0, N%8==0.
// ---------------------------------------------------------------------------
template <int MODE>
__global__ __launch_bounds__(256) void gemm_h(
    const f16* __restrict__ A, const f16* __restrict__ Bg, void* __restrict__ Cg,
    int M, int K, int N, int ldc, long long sB, long long sC)
{
    const f16* B = Bg + (size_t)blockIdx.z * sB;

    __shared__ f16 Ah[128][LDH];
    __shared__ f16 Bt[128][LDH];   // B transposed: Bt[n][k ^ swz(n)]

    const int tid  = threadIdx.x;
    const int lane = tid & 63;
    const int wv   = tid >> 6;
    const int wm   = wv >> 1, wn = wv & 1;
    const int ln   = lane & 15;
    const int q    = lane >> 4;

    const int row0 = blockIdx.y * 128;
    const int col0 = blockIdx.x * 128;

    const int am = tid >> 1;           // A-stage row 0..127
    const int ak = (tid & 1) << 4;     // A-stage k 0/16
    const int bk = tid >> 3;           // B-stage k 0..31
    const int bn = (tid & 7) << 4;     // B-stage col 0..112

    f32x4 acc[4][4];
#pragma unroll
    for (int i = 0; i < 4; ++i)
#pragma unroll
        for (int j = 0; j < 4; ++j) acc[i][j] = (f32x4){0.f, 0.f, 0.f, 0.f};

    for (int k0 = 0; k0 < K; k0 += 32) {
        const uint4 a0 = *(const uint4*)(A + (size_t)(row0 + am) * K + k0 + ak);
        const uint4 a1 = *(const uint4*)(A + (size_t)(row0 + am) * K + k0 + ak + 8);
        uint4 b0 = make_uint4(0, 0, 0, 0), b1 = make_uint4(0, 0, 0, 0);
        const int cb = col0 + bn;
        const f16* Brow = B + (size_t)(k0 + bk) * N;
        if (cb + 8  <= N) b0 = *(const uint4*)(Brow + cb);
        if (cb + 16 <= N) b1 = *(const uint4*)(Brow + cb + 8);

        __syncthreads();
        *(uint4*)&Ah[am][ak]     = a0;
        *(uint4*)&Ah[am][ak + 8] = a1;
        const f16* h0 = (const f16*)&b0;
        const f16* h1 = (const f16*)&b1;
#pragma unroll
        for (int j = 0; j < 8; ++j) {
            int n = bn + j;
            Bt[n][bk ^ (((n >> 4) & 3) << 3)] = h0[j];
        }
#pragma unroll
        for (int j = 0; j < 8; ++j) {
            int n = bn + 8 + j;
            Bt[n][bk ^ (((n >> 4) & 3) << 3)] = h1[j];
        }
        __syncthreads();

        half8 af[4], bf[4];
#pragma unroll
        for (int i = 0; i < 4; ++i)
            af[i] = *(const half8*)&Ah[wm * 64 + i * 16 + ln][q * 8];
#pragma unroll
        for (int j = 0; j < 4; ++j) {
            const int nb = wn * 64 + j * 16 + ln;
            const int sw = ((wn * 4 + j) & 3) << 3;
            bf[j] = *(const half8*)&Bt[nb][(q * 8) ^ sw];
        }
#pragma unroll
        for (int i = 0; i < 4; ++i)
#pragma unroll
            for (int j = 0; j < 4; ++j)
                acc[i][j] = __builtin_amdgcn_mfma_f32_16x16x32_f16(af[i], bf[j], acc[i][j], 0, 0, 0);
    }

    const size_t zoff = (size_t)blockIdx.z * sC;
#pragma unroll
    for (int i = 0; i < 4; ++i) {
#pragma unroll
        for (int j = 0; j < 4; ++j) {
            const int c = col0 + wn * 64 + j * 16 + ln;
            if (c < N) {
#pragma unroll
                for (int t = 0; t < 4; ++t) {
                    const int r = row0 + wm * 64 + i * 16 + q * 4 + t;
                    const size_t o = zoff + (size_t)r * ldc + c;
                    const float v = acc[i][j][t];
                    if (MODE == 0)      ((f16*)Cg)[o] = (f16)v;
                    else if (MODE == 1) ((float*)Cg)[o] = v;
                    else                ((float*)Cg)[o] += v;
                }
            }
        }
    }
}

// ---------------------------------------------------------------------------
// fp64 GEMM (pool-argmax-critical path; unchanged from R3 — verified).
// ---------------------------------------------------------------------------
__device__ inline void loadA4(const float* p, double* d) {
    float4 v = *(const float4*)p;
    d[0] = v.x; d[1] = v.y; d[2] = v.z; d[3] = v.w;
}
__device__ inline void loadA4(const double* p, double* d) {
    double2 v0 = *(const double2*)p, v1 = *(const double2*)(p + 2);
    d[0] = v0.x; d[1] = v0.y; d[2] = v1.x; d[3] = v1.y;
}

template <typename TA>
__global__ __launch_bounds__(256) void gemm_f64(
    const TA* __restrict__ A, const double* __restrict__ B, double* __restrict__ C,
    int M, int K, int N, int accum)
{
    __shared__ double As[16][64];
    __shared__ double Bs[16][64];

    const int tid  = threadIdx.x;
    const int tx   = tid & 15;
    const int ty   = tid >> 4;
    const int row0 = blockIdx.y * 64;
    const int col0 = blockIdx.x * 64;

    const int ra = tid >> 2;
    const int ka = (tid & 3) << 2;
    const int kb = tid >> 4;
    const int cb = (tid & 15) << 2;

    double acc[4][4];
#pragma unroll
    for (int i = 0; i < 4; ++i)
#pragma unroll
        for (int j = 0; j < 4; ++j) acc[i][j] = 0.0;

    for (int k0 = 0; k0 < K; k0 += 16) {
        double av[4];
        loadA4(A + (size_t)(row0 + ra) * K + k0 + ka, av);
        double2 b0 = {0.0, 0.0}, b1 = {0.0, 0.0};
        const int cbase = col0 + cb;
        if (cbase < N) {
            b0 = *(const double2*)(B + (size_t)(k0 + kb) * N + cbase);
            b1 = *(const double2*)(B + (size_t)(k0 + kb) * N + cbase + 2);
        }
        __syncthreads();
        As[ka + 0][ra] = av[0]; As[ka + 1][ra] = av[1];
        As[ka + 2][ra] = av[2]; As[ka + 3][ra] = av[3];
        *(double2*)&Bs[kb][cb]     = b0;
        *(double2*)&Bs[kb][cb + 2] = b1;
        __syncthreads();

#pragma unroll
        for (int kk = 0; kk < 16; ++kk) {
            double ar[4], br[4];
            ar[0] = As[kk][(ty << 2) + 0]; ar[1] = As[kk][(ty << 2) + 1];
            ar[2] = As[kk][(ty << 2) + 2]; ar[3] = As[kk][(ty << 2) + 3];
            br[0] = Bs[kk][(tx << 2) + 0]; br[1] = Bs[kk][(tx << 2) + 1];
            br[2] = Bs[kk][(tx << 2) + 2]; br[3] = Bs[kk][(tx << 2) + 3];
#pragma unroll
            for (int i = 0; i < 4; ++i)
#pragma unroll
                for (int j = 0; j < 4; ++j)
                    acc[i][j] = fma(ar[i], br[j], acc[i][j]);
        }
    }

#pragma unroll
    for (int i = 0; i < 4; ++i) {
        const int r = row0 + (ty << 2) + i;
#pragma unroll
        for (int j = 0; j < 4; ++j) {
            const int c = col0 + (tx << 2) + j;
            if (c < N) {
                double* p = C + (size_t)r * N + c;
                double v = acc[i][j];
                if (accum) v += *p;
                *p = v;
            }
        }
    }
}

// ---------------------------------------------------------------------------
// Aux kernels. Activation layout: [g=4][node][b=8][C].
// ---------------------------------------------------------------------------
__global__ void zero_k(float* __restrict__ p, int n) {
    int i = blockIdx.x * blockDim.x + threadIdx.x;
    if (i < n) p[i] = 0.f;
}

__global__ void cast16_k(const float* __restrict__ s, f16* __restrict__ d, int n) {
    int i = blockIdx.x * blockDim.x + threadIdx.x;
    if (i < n) d[i] = (f16)s[i];
}

// x [32][3072][32] fp32 -> XT64 [g][n][bi][32] fp64
__global__ void regroup_in64_k(const float* __restrict__ x, double* __restrict__ XT, int total) {
    int i = blockIdx.x * blockDim.x + threadIdx.x;
    if (i >= total) return;
    int c = i & 31;
    int t = i >> 5;
    int n = t % 3072;
    int b = t / 3072;
    XT[((((size_t)(b >> 3) * 3072 + n) << 3) + (b & 7)) * 32 + c] = (double)x[i];
}

// fp16 combine: wa=w0-w2, wb=w1, wc=2*w2
__global__ void cheb_combine16_k(const float* __restrict__ w, f16* __restrict__ wa,
                                 f16* __restrict__ wb, f16* __restrict__ wc, int n) {
    int i = blockIdx.x * blockDim.x + threadIdx.x;
    if (i >= n) return;
    float w0 = w[i], w1 = w[n + i], w2 = w[2 * n + i];
    wa[i] = (f16)(w0 - w2); wb[i] = (f16)w1; wc[i] = (f16)(2.f * w2);
}
// fp64 combine (encoder)
__global__ void cheb_combine64_k(const float* __restrict__ w, double* __restrict__ wa,
                                 double* __restrict__ wb, double* __restrict__ wc, int n) {
    int i = blockIdx.x * blockDim.x + threadIdx.x;
    if (i >= n) return;
    double w0 = w[i], w1 = w[n + i], w2 = w[2 * n + i];
    wa[i] = w0 - w2; wb[i] = w1; wc[i] = 2.0 * w2;
}

__global__ void transpose_w16_k(const float* __restrict__ w, f16* __restrict__ wt, int R, int Ccol) {
    int i = blockIdx.x * blockDim.x + threadIdx.x;
    if (i >= R * Ccol) return;
    int r = i / Ccol, c = i - r * Ccol;
    wt[(size_t)c * R + r] = (f16)w[i];
}
__global__ void transpose_w64_k(const float* __restrict__ w, double* __restrict__ wt, int R, int Ccol) {
    int i = blockIdx.x * blockDim.x + threadIdx.x;
    if (i >= R * Ccol) return;
    int r = i / Ccol, c = i - r * Ccol;
    wt[(size_t)c * R + r] = (double)w[i];
}

// fp32 BN (stats; apply in-place + optional f16 mirror)
__global__ void bn_reduce_k(const float* __restrict__ X, float* __restrict__ stats,
                            int rows, int ld, int off) {
    int c = threadIdx.x;
    float s = 0.f, s2 = 0.f;
    for (int r = blockIdx.x; r < rows; r += gridDim.x) {
        float v = X[(size_t)r * ld + off + c];
        s += v; s2 += v * v;
    }
    atomicAdd(&stats[c], s);
    atomicAdd(&stats[256 + c], s2);
}
__global__ void bn_apply_k(float* X, const float* __restrict__ stats,
                           const float* __restrict__ g, const float* __restrict__ be,
                           const float* rbias, f16* mirror,
                           int total, int C, float invN, int ld, int off) {
    int i = blockIdx.x * blockDim.x + threadIdx.x;
    if (i >= total) return;
    int c = i % C;
    int row = i / C;
    size_t a = (size_t)row * ld + off + c;
    float mu = stats[c] * invN;
    float var = stats[256 + c] * invN - mu * mu;
    float sc = g[c] * rsqrtf(var + 1e-5f);
    float v = (X[a] - mu) * sc + be[c];
    v = fmaxf(v, 0.f);
    if (rbias) v += rbias[c];
    X[a] = v;
    if (mirror) mirror[a] = (f16)v;
}

// fp64 BN (encoder)
__global__ void bn_reduce64_k(const double* __restrict__ X, double* __restrict__ stats,
                              int rows, int ld) {
    int c = threadIdx.x;
    double s = 0.0, s2 = 0.0;
    for (int r = blockIdx.x; r < rows; r += gridDim.x) {
        double v = X[(size_t)r * ld + c];
        s += v; s2 += v * v;
    }
    atomicAdd(&stats[c], s);
    atomicAdd(&stats[256 + c], s2);
}
__global__ void bn_apply64_k(double* X, const double* __restrict__ stats,
                             const float* __restrict__ g, const float* __restrict__ be,
                             const float* rbias, int total, int C, double invN) {
    int i = blockIdx.x * blockDim.x + threadIdx.x;
    if (i >= total) return;
    int c = i % C;
    double mu = stats[c] * invN;
    double var = stats[256 + c] * invN - mu * mu;
    double sc = (double)g[c] / sqrt(var + 1e-5);
    double v = (X[i] - mu) * sc + (double)be[c];
    v = v > 0.0 ? v : 0.0;
    if (rbias) v += (double)rbias[c];
    X[i] = v;
}

// fp64 e1 [row][128] -> CATh high half (f16, ld 256, off 128)
__global__ void cast_e1_k(const double* __restrict__ E1, f16* __restrict__ cat, int total) {
    int i = blockIdx.x * blockDim.x + threadIdx.x;
    if (i >= total) return;
    int c = i & 127;
    int row = i >> 7;
    cat[(size_t)row * 256 + 128 + c] = (f16)E1[i];
}

// pool 4 consecutive nodes of fp64 e1 -> Ph f16 [g][q][b][128], IDX node index
__global__ void pool4_64_k(const double* __restrict__ e1, f16* __restrict__ p,
                           int* __restrict__ idx, int total) {
    int i = blockIdx.x * blockDim.x + threadIdx.x;
    if (i >= total) return;
    int c = i & 127;
    int t = i >> 7;
    int b = t & 7;
    t >>= 3;
    int q = t % 768;
    int g = t / 768;
    size_t base = ((((size_t)g * 3072 + 4 * q) << 3) + b) * 128 + c;
    double best = e1[base];
    int bj = 0;
#pragma unroll
    for (int j = 1; j < 4; ++j) {
        double v = e1[base + (size_t)j * 1024];
        if (v > best) { best = v; bj = j; }   // strict >: first occurrence (jnp.argmax)
    }
    p[i] = (f16)best;
    idx[i] = 4 * q + bj;
}

// scatter e2 (fp32) into CATh low half (f16)
__global__ void unpool_cat_k(const float* __restrict__ e2, const int* __restrict__ idx,
                             f16* __restrict__ cat, int total) {
    int i = blockIdx.x * blockDim.x + threadIdx.x;
    if (i >= total) return;
    int c = i & 127;
    int t = i >> 7;
    int b = t & 7;
    t >>= 3;
    int q = t % 768;
    int g = t / 768;
    f16 val = (f16)e2[i];
    int id = idx[i];
    size_t base = ((((size_t)g * 3072 + 4 * q) << 3) + b) * 256 + c;
#pragma unroll
    for (int j = 0; j < 4; ++j)
        cat[base + (size_t)j * 2048] = (4 * q + j == id) ? val : (f16)0.f;
}

// O [g][n][bi][8] fp32 -> out [B][N][8], + bias
__global__ void transpose_out_k(const float* __restrict__ O, const float* __restrict__ bias,
                                float* __restrict__ out, int total) {
    int i = blockIdx.x * blockDim.x + threadIdx.x;
    if (i >= total) return;
    int c = i & 7;
    int t = i >> 3;
    int n = t % 3072;
    int b = t / 3072;
    out[i] = O[((((size_t)(b >> 3) * 3072 + n) << 3) + (b & 7)) * 8 + c] + bias[c];
}

// ---------------------------------------------------------------------------
extern "C" void kernel_launch(void* const* d_in, const int* in_sizes, int n_in,
                              void* d_out, int out_size, void* d_ws, size_t ws_size,
                              hipStream_t stream)
{
    (void)in_sizes; (void)n_in; (void)out_size; (void)ws_size;

    const float* x    = (const float*)d_in[0];
    const float* L0   = (const float*)d_in[1];
    const float* L1   = (const float*)d_in[2];
    const float* w11  = (const float*)d_in[3];
    const float* g11  = (const float*)d_in[5];
    const float* be11 = (const float*)d_in[6];
    const float* w13  = (const float*)d_in[7];
    const float* g13  = (const float*)d_in[9];
    const float* be13 = (const float*)d_in[10];
    const float* wr1  = (const float*)d_in[11];
    const float* br1  = (const float*)d_in[12];
    const float* w21  = (const float*)d_in[13];
    const float* g21  = (const float*)d_in[15];
    const float* be21 = (const float*)d_in[16];
    const float* w23  = (const float*)d_in[17];
    const float* g23  = (const float*)d_in[19];
    const float* be23 = (const float*)d_in[20];
    const float* wr2  = (const float*)d_in[21];
    const float* br2  = (const float*)d_in[22];
    const float* uw11 = (const float*)d_in[23];
    const float* ug11 = (const float*)d_in[25];
    const float* ube11= (const float*)d_in[26];
    const float* uw12 = (const float*)d_in[27];
    const float* ug12 = (const float*)d_in[29];
    const float* ube12= (const float*)d_in[30];
    const float* uwr1 = (const float*)d_in[31];
    const float* ubr1 = (const float*)d_in[32];
    const float* uw13 = (const float*)d_in[33];
    const float* ub13 = (const float*)d_in[34];
    float* out = (float*)d_out;

    float* ws = (float*)d_ws;
    size_t off = 0;
    auto alloc = [&](size_t n) { float* p = ws + off; off += (n + 63) & ~(size_t)63; return p; };

    // ---- regions (floats). Total ~224 MiB. ----
    float* R1 = alloc(12582912);   // CATh f16[25165824] | p1: H1 dbl[6291456]
    float* R2 = alloc(25165824);   // D1 fp32(12.58M: H2@0, Y3@+4718592, O@0) + H64 fp32(6.29M)
                                   //  + T1h f16 + T2h f16 | p1: E1 dbl[12582912]
    float* R3 = alloc(6291456);    // p1: XT64 dbl[3145728] | p2: H2h f16 then D1h f16[12582912]
    float* R4 = alloc(6291456);    // p1: T1d+T2d dbl | p2: Ph f16[3145728] + H64h f16[6291456]
    int*  IDX = (int*)alloc(3145728);
    float* L0f = alloc(4718592);   // L0h f16[9437184]
    float* L1f = alloc(294912);    // L1h f16[589824]
    float* ST  = alloc(1536);      // fp32 stats [0..512), fp64 stats [512..1536)

    // f16 weights
    f16* wa21h = (f16*)alloc(12288); f16* wb21h = (f16*)alloc(12288); f16* wc21h = (f16*)alloc(12288);
    f16* wa23h = (f16*)alloc(12288); f16* wb23h = (f16*)alloc(12288); f16* wc23h = (f16*)alloc(12288);
    f16* wau11h = (f16*)alloc(16384); f16* wbu11h = (f16*)alloc(16384); f16* wcu11h = (f16*)alloc(16384);
    f16* wau12h = (f16*)alloc(4096);  f16* wbu12h = (f16*)alloc(4096);  f16* wcu12h = (f16*)alloc(4096);
    f16* wau13h = (f16*)alloc(256);   f16* wbu13h = (f16*)alloc(256);   f16* wcu13h = (f16*)alloc(256);
    f16* wr2Th  = (f16*)alloc(8192);
    f16* uwr1Th = (f16*)alloc(8192);

    // fp64 weights (encoder)
    double* wa11_64 = (double*)alloc(4096);
    double* wb11_64 = (double*)alloc(4096);
    double* wc11_64 = (double*)alloc(4096);
    double* wa13_64 = (double*)alloc(16384);
    double* wb13_64 = (double*)alloc(16384);
    double* wc13_64 = (double*)alloc(16384);
    double* wr1T_64 = (double*)alloc(8192);

    // ---- aliases ----
    f16*    CATh = (f16*)R1;
    double* H1   = (double*)R1;
    float*  D1   = R2;                       // [g][n][b][128] fp32
    float*  H2   = R2;                       // [g][q][b][192] fp32 (inside D1 region)
    float*  Y3   = R2 + 4718592;             // [g][q][b][128] fp32 (inside D1 region)
    float*  O    = R2;                       // final [g][n][b][8] fp32
    float*  H64  = R2 + 12582912;            // [g][n][b][64] fp32
    f16*    T1h  = (f16*)(R2 + 18874368);    // f16[6291456]
    f16*    T2h  = (f16*)(R2 + 22020096);    // f16[6291456]
    double* E1   = (double*)R2;              // dbl[12582912] spans R2
    double* XT64 = (double*)R3;
    f16*    H2h  = (f16*)R3;                 // early phase-2
    f16*    D1h  = (f16*)R3;                 // late phase-2 (H2h dead)
    double* T1d  = (double*)R4;
    double* T2d  = (double*)(R4 + 3145728);
    f16*    Ph   = (f16*)R4;                 // f16[3145728]
    f16*    H64h = (f16*)(R4 + 1572864);     // f16[6291456]
    f16*    L0h  = (f16*)L0f;
    f16*    L1h  = (f16*)L1f;
    double* ST64 = (double*)(ST + 512);

    auto gh = [&](int mode, const f16* A, const f16* B, void* C, int M, int K, int N,
                  int ldc, long long sB, long long sC, int z) {
        dim3 grid((N + 127) / 128, M / 128, z);
        if (mode == 0)      gemm_h<0><<<grid, 256, 0, stream>>>(A, B, C, M, K, N, ldc, sB, sC);
        else if (mode == 1) gemm_h<1><<<grid, 256, 0, stream>>>(A, B, C, M, K, N, ldc, sB, sC);
        else                gemm_h<2><<<grid, 256, 0, stream>>>(A, B, C, M, K, N, ldc, sB, sC);
    };
    auto gemm64f = [&](const float* A, const double* B, double* C, int M, int K, int N, int accum) {
        dim3 grid((N + 63) / 64, M / 64);
        gemm_f64<float><<<grid, 256, 0, stream>>>(A, B, C, M, K, N, accum);
    };
    auto gemm64d = [&](const double* A, const double* B, double* C, int M, int K, int N, int accum) {
        dim3 grid((N + 63) / 64, M / 64);
        gemm_f64<double><<<grid, 256, 0, stream>>>(A, B, C, M, K, N, accum);
    };
    auto bn = [&](float* X, int rows, int C, int ld, int offc,
                  const float* gp, const float* bep, const float* rbias, f16* mirror) {
        zero_k<<<2, 256, 0, stream>>>(ST, 512);
        bn_reduce_k<<<384, C, 0, stream>>>(X, ST, rows, ld, offc);
        int total = rows * C;
        bn_apply_k<<<(total + 255) / 256, 256, 0, stream>>>(
            X, ST, gp, bep, rbias, mirror, total, C, 1.f / (float)rows, ld, offc);
    };
    auto bn64 = [&](double* X, int rows, int C,
                    const float* gp, const float* bep, const float* rbias) {
        zero_k<<<4, 256, 0, stream>>>(ST + 512, 1024);
        bn_reduce64_k<<<384, C, 0, stream>>>(X, ST64, rows, C);
        int total = rows * C;
        bn_apply64_k<<<(total + 255) / 256, 256, 0, stream>>>(
            X, ST64, gp, bep, rbias, total, C, 1.0 / (double)rows);
    };
    auto comb16 = [&](const float* w, f16* a, f16* b, f16* c, int n) {
        cheb_combine16_k<<<(n + 255) / 256, 256, 0, stream>>>(w, a, b, c, n);
    };

    // ---- weight prep ----
    cheb_combine64_k<<<8, 256, 0, stream>>>(w11, wa11_64, wb11_64, wc11_64, 2048);
    cheb_combine64_k<<<32, 256, 0, stream>>>(w13, wa13_64, wb13_64, wc13_64, 8192);
    transpose_w64_k<<<16, 256, 0, stream>>>(wr1, wr1T_64, 128, 32);
    comb16(w21,  wa21h,  wb21h,  wc21h,  24576);
    comb16(w23,  wa23h,  wb23h,  wc23h,  24576);
    comb16(uw11, wau11h, wbu11h, wcu11h, 32768);
    comb16(uw12, wau12h, wbu12h, wcu12h, 8192);
    comb16(uw13, wau13h, wbu13h, wcu13h, 512);
    transpose_w16_k<<<64, 256, 0, stream>>>(wr2, wr2Th, 128, 128);
    transpose_w16_k<<<64, 256, 0, stream>>>(uwr1, uwr1Th, 64, 256);
    cast16_k<<<36864, 256, 0, stream>>>(L0, L0h, 9437184);
    cast16_k<<<2304, 256, 0, stream>>>(L1, L1h, 589824);
    regroup_in64_k<<<12288, 256, 0, stream>>>(x, XT64, 3145728);

    // ==== PHASE 1 (fp64): encoder to e1, exact argmax ====
    for (int g = 0; g < 4; ++g) {
        const double* Xg = XT64 + (size_t)g * 786432;
        double* Hg = H1 + (size_t)g * 1572864;
        gemm64f(L0, Xg, T1d, 3072, 3072, 256, 0);
        gemm64f(L0, T1d, T2d, 3072, 3072, 256, 0);
        gemm64d(Xg,  wa11_64, Hg, 24576, 32, 64, 0);
        gemm64d(T1d, wb11_64, Hg, 24576, 32, 64, 1);
        gemm64d(T2d, wc11_64, Hg, 24576, 32, 64, 1);
    }
    bn64(H1, 98304, 64, g11, be11, nullptr);                 // h1

    for (int g = 0; g < 4; ++g) {
        const double* Hg = H1 + (size_t)g * 1572864;
        double* Eg = E1 + (size_t)g * 3145728;
        gemm64f(L0, Hg, T1d, 3072, 3072, 512, 0);
        gemm64f(L0, T1d, T2d, 3072, 3072, 512, 0);
        gemm64d(Hg,  wa13_64, Eg, 24576, 64, 128, 0);
        gemm64d(T1d, wb13_64, Eg, 24576, 64, 128, 1);
        gemm64d(T2d, wc13_64, Eg, 24576, 64, 128, 1);
    }
    bn64(E1, 98304, 128, g13, be13, br1);
    gemm64d(XT64, wr1T_64, E1, 98304, 32, 128, 1);           // e1 (fp64)

    // transition: pool on fp64; CATh high = f16(e1)
    pool4_64_k<<<12288, 256, 0, stream>>>(E1, Ph, IDX, 3145728);
    cast_e1_k<<<49152, 256, 0, stream>>>(E1, CATh, 12582912);
    // E1 / XT64 / H1 / T1d / T2d dead from here.

    // ==== PHASE 2 (fp16 MFMA) ====
    // L2 conv1: 128 -> 192
    gh(0, L1h, Ph, T1h, 768, 768, 1024, 1024, 786432, 786432, 4);
    gh(0, L1h, T1h, T2h, 768, 768, 1024, 1024, 786432, 786432, 4);
    gh(1, Ph,  wa21h, H2, 24576, 128, 192, 192, 0, 0, 1);
    gh(2, T1h, wb21h, H2, 24576, 128, 192, 192, 0, 0, 1);
    gh(2, T2h, wc21h, H2, 24576, 128, 192, 192, 0, 0, 1);
    bn(H2, 24576, 192, 192, 0, g21, be21, nullptr, H2h);     // h2 (+f16 mirror)

    // L2 conv2: 192 -> 128, + residual -> e2 (Y3)
    gh(0, L1h, H2h, T1h, 768, 768, 1536, 1536, 1179648, 1179648, 4);
    gh(0, L1h, T1h, T2h, 768, 768, 1536, 1536, 1179648, 1179648, 4);
    gh(1, H2h, wa23h, Y3, 24576, 192, 128, 128, 0, 0, 1);
    gh(2, T1h, wb23h, Y3, 24576, 192, 128, 128, 0, 0, 1);
    gh(2, T2h, wc23h, Y3, 24576, 192, 128, 128, 0, 0, 1);
    bn(Y3, 24576, 128, 128, 0, g23, be23, br2, nullptr);
    gh(2, Ph, wr2Th, Y3, 24576, 128, 128, 128, 0, 0, 1);     // e2

    // unpool into CATh low (f16)
    unpool_cat_k<<<12288, 256, 0, stream>>>(Y3, IDX, CATh, 3145728);

    // dec conv1: 256 -> 128 (per group)
    for (int g = 0; g < 4; ++g) {
        const f16* Bg = CATh + (size_t)g * 6291456;
        float* Dg = D1 + (size_t)g * 3145728;
        gh(0, L0h, Bg, T1h, 3072, 3072, 2048, 2048, 0, 0, 1);
        gh(0, L0h, T1h, T2h, 3072, 3072, 2048, 2048, 0, 0, 1);
        gh(1, Bg,  wau11h, Dg, 24576, 256, 128, 128, 0, 0, 1);
        gh(2, T1h, wbu11h, Dg, 24576, 256, 128, 128, 0, 0, 1);
        gh(2, T2h, wcu11h, Dg, 24576, 256, 128, 128, 0, 0, 1);
    }
    bn(D1, 98304, 128, 128, 0, ug11, ube11, nullptr, D1h);   // d1 (+f16 mirror)

    // dec conv2: 128 -> 64, + residual from cat
    for (int g = 0; g < 4; ++g) {
        const f16* Bg = D1h + (size_t)g * 3145728;   // FIX (was 6291456): 128-ch group stride
        float* Dg = H64 + (size_t)g * 1572864;
        gh(0, L0h, Bg, T1h, 3072, 3072, 1024, 1024, 0, 0, 1);
        gh(0, L0h, T1h, T2h, 3072, 3072, 1024, 1024, 0, 0, 1);
        gh(1, Bg,  wau12h, Dg, 24576, 128, 64, 64, 0, 0, 1);
        gh(2, T1h, wbu12h, Dg, 24576, 128, 64, 64, 0, 0, 1);
        gh(2, T2h, wcu12h, Dg, 24576, 128, 64, 64, 0, 0, 1);
    }
    bn(H64, 98304, 64, 64, 0, ug12, ube12, ubr1, nullptr);
    gh(2, CATh, uwr1Th, H64, 98304, 256, 64, 64, 0, 0, 1);   // d2 = bn + residual
    cast16_k<<<24576, 256, 0, stream>>>(H64, H64h, 6291456); // d2 f16 mirror

    // final conv: 64 -> 8
    gh(0, L0h, H64h, T1h, 3072, 3072, 512, 512, 1572864, 1572864, 4);
    gh(0, L0h, T1h, T2h, 3072, 3072, 512, 512, 1572864, 1572864, 4);
    gh(1, H64h, wau13h, O, 98304, 64, 8, 8, 0, 0, 1);
    gh(2, T1h,  wbu13h, O, 98304, 64, 8, 8, 0, 0, 1);
    gh(2, T2h,  wcu13h, O, 98304, 64, 8, 8, 0, 0, 1);

    transpose_out_k<<<3072, 256, 0, stream>>>(O, ub13, out, 786432);
}

// Round 6
// 6917.556 us; speedup vs baseline: 2.4469x; 1.3313x over previous
//
#include <hip/hip_runtime.h>

typedef _Float16 f16;
typedef f16   half8 __attribute__((ext_vector_type(8)));
typedef float f32x4 __attribute__((ext_vector_type(4)));

#define LDH 40   // padded halves per LDS row (16B-aligned rows, conflict-reducing)

// ---------------------------------------------------------------------------
// fp16 MFMA GEMM: C[M,N] = A[M,K]*B[K,N]; A,B fp16 row-major; C per MODE.
// MODE 0: f16 store; 1: f32 store; 2: f32 accumulate-add.
// blockIdx.z batches B/C by sB/sC (element strides). M%128==0, K%32==0, N%8==0.
// ---------------------------------------------------------------------------
template <int MODE>
__global__ __launch_bounds__(256) void gemm_h(
    const f16* __restrict__ A, const f16* __restrict__ Bg, void* __restrict__ Cg,
    int M, int K, int N, int ldc, long long sB, long long sC)
{
    const f16* B = Bg + (size_t)blockIdx.z * sB;

    __shared__ f16 Ah[128][LDH];
    __shared__ f16 Bt[128][LDH];   // B transposed: Bt[n][k ^ swz(n)]

    const int tid  = threadIdx.x;
    const int lane = tid & 63;
    const int wv   = tid >> 6;
    const int wm   = wv >> 1, wn = wv & 1;
    const int ln   = lane & 15;
    const int q    = lane >> 4;

    const int row0 = blockIdx.y * 128;
    const int col0 = blockIdx.x * 128;

    const int am = tid >> 1;           // A-stage row 0..127
    const int ak = (tid & 1) << 4;     // A-stage k 0/16
    const int bk = tid >> 3;           // B-stage k 0..31
    const int bn = (tid & 7) << 4;     // B-stage col 0..112

    f32x4 acc[4][4];
#pragma unroll
    for (int i = 0; i < 4; ++i)
#pragma unroll
        for (int j = 0; j < 4; ++j) acc[i][j] = (f32x4){0.f, 0.f, 0.f, 0.f};

    for (int k0 = 0; k0 < K; k0 += 32) {
        const uint4 a0 = *(const uint4*)(A + (size_t)(row0 + am) * K + k0 + ak);
        const uint4 a1 = *(const uint4*)(A + (size_t)(row0 + am) * K + k0 + ak + 8);
        uint4 b0 = make_uint4(0, 0, 0, 0), b1 = make_uint4(0, 0, 0, 0);
        const int cb = col0 + bn;
        const f16* Brow = B + (size_t)(k0 + bk) * N;
        if (cb + 8  <= N) b0 = *(const uint4*)(Brow + cb);
        if (cb + 16 <= N) b1 = *(const uint4*)(Brow + cb + 8);

        __syncthreads();
        *(uint4*)&Ah[am][ak]     = a0;
        *(uint4*)&Ah[am][ak + 8] = a1;
        const f16* h0 = (const f16*)&b0;
        const f16* h1 = (const f16*)&b1;
#pragma unroll
        for (int j = 0; j < 8; ++j) {
            int n = bn + j;
            Bt[n][bk ^ (((n >> 4) & 3) << 3)] = h0[j];
        }
#pragma unroll
        for (int j = 0; j < 8; ++j) {
            int n = bn + 8 + j;
            Bt[n][bk ^ (((n >> 4) & 3) << 3)] = h1[j];
        }
        __syncthreads();

        half8 af[4], bf[4];
#pragma unroll
        for (int i = 0; i < 4; ++i)
            af[i] = *(const half8*)&Ah[wm * 64 + i * 16 + ln][q * 8];
#pragma unroll
        for (int j = 0; j < 4; ++j) {
            const int nb = wn * 64 + j * 16 + ln;
            const int sw = ((wn * 4 + j) & 3) << 3;
            bf[j] = *(const half8*)&Bt[nb][(q * 8) ^ sw];
        }
#pragma unroll
        for (int i = 0; i < 4; ++i)
#pragma unroll
            for (int j = 0; j < 4; ++j)
                acc[i][j] = __builtin_amdgcn_mfma_f32_16x16x32_f16(af[i], bf[j], acc[i][j], 0, 0, 0);
    }

    const size_t zoff = (size_t)blockIdx.z * sC;
#pragma unroll
    for (int i = 0; i < 4; ++i) {
#pragma unroll
        for (int j = 0; j < 4; ++j) {
            const int c = col0 + wn * 64 + j * 16 + ln;
            if (c < N) {
#pragma unroll
                for (int t = 0; t < 4; ++t) {
                    const int r = row0 + wm * 64 + i * 16 + q * 4 + t;
                    const size_t o = zoff + (size_t)r * ldc + c;
                    const float v = acc[i][j][t];
                    if (MODE == 0)      ((f16*)Cg)[o] = (f16)v;
                    else if (MODE == 1) ((float*)Cg)[o] = v;
                    else                ((float*)Cg)[o] += v;
                }
            }
        }
    }
}

// ---------------------------------------------------------------------------
// fp64 GEMM (pool-argmax-critical path). TILE 64, BK 16, 256 thr, 4x4 micro.
// Micro-tile col = tx + 16*j -> B LDS reads stride-1 (conflict-free),
// C stores 128B-contiguous. blockIdx.z batches B/C by sB/sC (double strides).
// A may be fp32 (converted on load) or fp64. M%64==0, K%16==0, N%4==0.
// ---------------------------------------------------------------------------
__device__ inline void loadA4(const float* p, double* d) {
    float4 v = *(const float4*)p;
    d[0] = v.x; d[1] = v.y; d[2] = v.z; d[3] = v.w;
}
__device__ inline void loadA4(const double* p, double* d) {
    double2 v0 = *(const double2*)p, v1 = *(const double2*)(p + 2);
    d[0] = v0.x; d[1] = v0.y; d[2] = v1.x; d[3] = v1.y;
}

template <typename TA>
__global__ __launch_bounds__(256) void gemm_f64(
    const TA* __restrict__ A, const double* __restrict__ Bg, double* __restrict__ Cg,
    int M, int K, int N, long long sB, long long sC, int accum)
{
    const double* B = Bg + (size_t)blockIdx.z * sB;
    double*       C = Cg + (size_t)blockIdx.z * sC;

    __shared__ double As[16][64];
    __shared__ double Bs[16][64];

    const int tid  = threadIdx.x;
    const int tx   = tid & 15;
    const int ty   = tid >> 4;
    const int row0 = blockIdx.y * 64;
    const int col0 = blockIdx.x * 64;

    const int ra = tid >> 2;
    const int ka = (tid & 3) << 2;
    const int kb = tid >> 4;
    const int cb = (tid & 15) << 2;

    double acc[4][4];
#pragma unroll
    for (int i = 0; i < 4; ++i)
#pragma unroll
        for (int j = 0; j < 4; ++j) acc[i][j] = 0.0;

    for (int k0 = 0; k0 < K; k0 += 16) {
        double av[4];
        loadA4(A + (size_t)(row0 + ra) * K + k0 + ka, av);
        double2 b0 = {0.0, 0.0}, b1 = {0.0, 0.0};
        const int cbase = col0 + cb;
        if (cbase < N) {
            b0 = *(const double2*)(B + (size_t)(k0 + kb) * N + cbase);
            b1 = *(const double2*)(B + (size_t)(k0 + kb) * N + cbase + 2);
        }
        __syncthreads();
        As[ka + 0][ra] = av[0]; As[ka + 1][ra] = av[1];
        As[ka + 2][ra] = av[2]; As[ka + 3][ra] = av[3];
        *(double2*)&Bs[kb][cb]     = b0;
        *(double2*)&Bs[kb][cb + 2] = b1;
        __syncthreads();

#pragma unroll
        for (int kk = 0; kk < 16; ++kk) {
            double ar[4], br[4];
            ar[0] = As[kk][(ty << 2) + 0]; ar[1] = As[kk][(ty << 2) + 1];
            ar[2] = As[kk][(ty << 2) + 2]; ar[3] = As[kk][(ty << 2) + 3];
            br[0] = Bs[kk][tx];      br[1] = Bs[kk][tx + 16];
            br[2] = Bs[kk][tx + 32]; br[3] = Bs[kk][tx + 48];
#pragma unroll
            for (int i = 0; i < 4; ++i)
#pragma unroll
                for (int j = 0; j < 4; ++j)
                    acc[i][j] = fma(ar[i], br[j], acc[i][j]);
        }
    }

#pragma unroll
    for (int i = 0; i < 4; ++i) {
        const int r = row0 + (ty << 2) + i;
#pragma unroll
        for (int j = 0; j < 4; ++j) {
            const int c = col0 + tx + 16 * j;
            if (c < N) {
                double* p = C + (size_t)r * N + c;
                double v = acc[i][j];
                if (accum) v += *p;
                *p = v;
            }
        }
    }
}

// ---------------------------------------------------------------------------
// Aux kernels. Activation layout: [g=4][node][b=8][C].
// ---------------------------------------------------------------------------
__global__ void zero_k(float* __restrict__ p, int n) {
    int i = blockIdx.x * blockDim.x + threadIdx.x;
    if (i < n) p[i] = 0.f;
}

__global__ void cast16_k(const float* __restrict__ s, f16* __restrict__ d, int n) {
    int i = blockIdx.x * blockDim.x + threadIdx.x;
    if (i < n) d[i] = (f16)s[i];
}

// x [32][3072][32] fp32 -> XT64 [g][n][bi][32] fp64
__global__ void regroup_in64_k(const float* __restrict__ x, double* __restrict__ XT, int total) {
    int i = blockIdx.x * blockDim.x + threadIdx.x;
    if (i >= total) return;
    int c = i & 31;
    int t = i >> 5;
    int n = t % 3072;
    int b = t / 3072;
    XT[((((size_t)(b >> 3) * 3072 + n) << 3) + (b & 7)) * 32 + c] = (double)x[i];
}

// fp16 combine: wa=w0-w2, wb=w1, wc=2*w2
__global__ void cheb_combine16_k(const float* __restrict__ w, f16* __restrict__ wa,
                                 f16* __restrict__ wb, f16* __restrict__ wc, int n) {
    int i = blockIdx.x * blockDim.x + threadIdx.x;
    if (i >= n) return;
    float w0 = w[i], w1 = w[n + i], w2 = w[2 * n + i];
    wa[i] = (f16)(w0 - w2); wb[i] = (f16)w1; wc[i] = (f16)(2.f * w2);
}
// fp64 combine (encoder)
__global__ void cheb_combine64_k(const float* __restrict__ w, double* __restrict__ wa,
                                 double* __restrict__ wb, double* __restrict__ wc, int n) {
    int i = blockIdx.x * blockDim.x + threadIdx.x;
    if (i >= n) return;
    double w0 = w[i], w1 = w[n + i], w2 = w[2 * n + i];
    wa[i] = w0 - w2; wb[i] = w1; wc[i] = 2.0 * w2;
}

__global__ void transpose_w16_k(const float* __restrict__ w, f16* __restrict__ wt, int R, int Ccol) {
    int i = blockIdx.x * blockDim.x + threadIdx.x;
    if (i >= R * Ccol) return;
    int r = i / Ccol, c = i - r * Ccol;
    wt[(size_t)c * R + r] = (f16)w[i];
}
__global__ void transpose_w64_k(const float* __restrict__ w, double* __restrict__ wt, int R, int Ccol) {
    int i = blockIdx.x * blockDim.x + threadIdx.x;
    if (i >= R * Ccol) return;
    int r = i / Ccol, c = i - r * Ccol;
    wt[(size_t)c * R + r] = (double)w[i];
}

// fp32 BN (stats; apply in-place + optional f16 mirror)
__global__ void bn_reduce_k(const float* __restrict__ X, float* __restrict__ stats,
                            int rows, int ld, int off) {
    int c = threadIdx.x;
    float s = 0.f, s2 = 0.f;
    for (int r = blockIdx.x; r < rows; r += gridDim.x) {
        float v = X[(size_t)r * ld + off + c];
        s += v; s2 += v * v;
    }
    atomicAdd(&stats[c], s);
    atomicAdd(&stats[256 + c], s2);
}
__global__ void bn_apply_k(float* X, const float* __restrict__ stats,
                           const float* __restrict__ g, const float* __restrict__ be,
                           const float* rbias, f16* mirror,
                           int total, int C, float invN, int ld, int off) {
    int i = blockIdx.x * blockDim.x + threadIdx.x;
    if (i >= total) return;
    int c = i % C;
    int row = i / C;
    size_t a = (size_t)row * ld + off + c;
    float mu = stats[c] * invN;
    float var = stats[256 + c] * invN - mu * mu;
    float sc = g[c] * rsqrtf(var + 1e-5f);
    float v = (X[a] - mu) * sc + be[c];
    v = fmaxf(v, 0.f);
    if (rbias) v += rbias[c];
    X[a] = v;
    if (mirror) mirror[a] = (f16)v;
}

// fp64 BN (encoder)
__global__ void bn_reduce64_k(const double* __restrict__ X, double* __restrict__ stats,
                              int rows, int ld) {
    int c = threadIdx.x;
    double s = 0.0, s2 = 0.0;
    for (int r = blockIdx.x; r < rows; r += gridDim.x) {
        double v = X[(size_t)r * ld + c];
        s += v; s2 += v * v;
    }
    atomicAdd(&stats[c], s);
    atomicAdd(&stats[256 + c], s2);
}
__global__ void bn_apply64_k(double* X, const double* __restrict__ stats,
                             const float* __restrict__ g, const float* __restrict__ be,
                             const float* rbias, int total, int C, double invN) {
    int i = blockIdx.x * blockDim.x + threadIdx.x;
    if (i >= total) return;
    int c = i % C;
    double mu = stats[c] * invN;
    double var = stats[256 + c] * invN - mu * mu;
    double sc = (double)g[c] / sqrt(var + 1e-5);
    double v = (X[i] - mu) * sc + (double)be[c];
    v = v > 0.0 ? v : 0.0;
    if (rbias) v += (double)rbias[c];
    X[i] = v;
}

// fp64 e1 [row][128] -> CATh high half (f16, ld 256, off 128)
__global__ void cast_e1_k(const double* __restrict__ E1, f16* __restrict__ cat, int total) {
    int i = blockIdx.x * blockDim.x + threadIdx.x;
    if (i >= total) return;
    int c = i & 127;
    int row = i >> 7;
    cat[(size_t)row * 256 + 128 + c] = (f16)E1[i];
}

// pool 4 consecutive nodes of fp64 e1 -> Ph f16 [g][q][b][128], IDX node index
__global__ void pool4_64_k(const double* __restrict__ e1, f16* __restrict__ p,
                           int* __restrict__ idx, int total) {
    int i = blockIdx.x * blockDim.x + threadIdx.x;
    if (i >= total) return;
    int c = i & 127;
    int t = i >> 7;
    int b = t & 7;
    t >>= 3;
    int q = t % 768;
    int g = t / 768;
    size_t base = ((((size_t)g * 3072 + 4 * q) << 3) + b) * 128 + c;
    double best = e1[base];
    int bj = 0;
#pragma unroll
    for (int j = 1; j < 4; ++j) {
        double v = e1[base + (size_t)j * 1024];
        if (v > best) { best = v; bj = j; }   // strict >: first occurrence (jnp.argmax)
    }
    p[i] = (f16)best;
    idx[i] = 4 * q + bj;
}

// scatter e2 (fp32) into CATh low half (f16)
__global__ void unpool_cat_k(const float* __restrict__ e2, const int* __restrict__ idx,
                             f16* __restrict__ cat, int total) {
    int i = blockIdx.x * blockDim.x + threadIdx.x;
    if (i >= total) return;
    int c = i & 127;
    int t = i >> 7;
    int b = t & 7;
    t >>= 3;
    int q = t % 768;
    int g = t / 768;
    f16 val = (f16)e2[i];
    int id = idx[i];
    size_t base = ((((size_t)g * 3072 + 4 * q) << 3) + b) * 256 + c;
#pragma unroll
    for (int j = 0; j < 4; ++j)
        cat[base + (size_t)j * 2048] = (4 * q + j == id) ? val : (f16)0.f;
}

// O [g][n][bi][8] fp32 -> out [B][N][8], + bias
__global__ void transpose_out_k(const float* __restrict__ O, const float* __restrict__ bias,
                                float* __restrict__ out, int total) {
    int i = blockIdx.x * blockDim.x + threadIdx.x;
    if (i >= total) return;
    int c = i & 7;
    int t = i >> 3;
    int n = t % 3072;
    int b = t / 3072;
    out[i] = O[((((size_t)(b >> 3) * 3072 + n) << 3) + (b & 7)) * 8 + c] + bias[c];
}

// ---------------------------------------------------------------------------
extern "C" void kernel_launch(void* const* d_in, const int* in_sizes, int n_in,
                              void* d_out, int out_size, void* d_ws, size_t ws_size,
                              hipStream_t stream)
{
    (void)in_sizes; (void)n_in; (void)out_size; (void)ws_size;

    const float* x    = (const float*)d_in[0];
    const float* L0   = (const float*)d_in[1];
    const float* L1   = (const float*)d_in[2];
    const float* w11  = (const float*)d_in[3];
    const float* g11  = (const float*)d_in[5];
    const float* be11 = (const float*)d_in[6];
    const float* w13  = (const float*)d_in[7];
    const float* g13  = (const float*)d_in[9];
    const float* be13 = (const float*)d_in[10];
    const float* wr1  = (const float*)d_in[11];
    const float* br1  = (const float*)d_in[12];
    const float* w21  = (const float*)d_in[13];
    const float* g21  = (const float*)d_in[15];
    const float* be21 = (const float*)d_in[16];
    const float* w23  = (const float*)d_in[17];
    const float* g23  = (const float*)d_in[19];
    const float* be23 = (const float*)d_in[20];
    const float* wr2  = (const float*)d_in[21];
    const float* br2  = (const float*)d_in[22];
    const float* uw11 = (const float*)d_in[23];
    const float* ug11 = (const float*)d_in[25];
    const float* ube11= (const float*)d_in[26];
    const float* uw12 = (const float*)d_in[27];
    const float* ug12 = (const float*)d_in[29];
    const float* ube12= (const float*)d_in[30];
    const float* uwr1 = (const float*)d_in[31];
    const float* ubr1 = (const float*)d_in[32];
    const float* uw13 = (const float*)d_in[33];
    const float* ub13 = (const float*)d_in[34];
    float* out = (float*)d_out;

    float* ws = (float*)d_ws;
    size_t off = 0;
    auto alloc = [&](size_t n) { float* p = ws + off; off += (n + 63) & ~(size_t)63; return p; };

    // ---- regions (floats). Total ~224 MiB. ----
    float* R1 = alloc(12582912);   // CATh f16[25165824] | p1: H1 dbl[6291456]
    float* R2 = alloc(25165824);   // D1 fp32 + H64 fp32 + T1h/T2h f16 | p1: E1 dbl[12582912]
    float* R3 = alloc(6291456);    // p1: XT64 dbl[3145728] | p2: H2h f16 then D1h f16
    float* R4 = alloc(6291456);    // p1: T1d dbl[3145728] | p2: Ph f16 + H64h f16
    int*  IDX = (int*)alloc(3145728);  // p1 (with L0f): T2d dbl[3145728]
    float* L0f = alloc(4718592);   // p2: L0h f16[9437184]
    float* L1f = alloc(294912);    // p2: L1h f16[589824]
    float* ST  = alloc(1536);      // fp32 stats [0..512), fp64 stats [512..1536)

    // f16 weights
    f16* wa21h = (f16*)alloc(12288); f16* wb21h = (f16*)alloc(12288); f16* wc21h = (f16*)alloc(12288);
    f16* wa23h = (f16*)alloc(12288); f16* wb23h = (f16*)alloc(12288); f16* wc23h = (f16*)alloc(12288);
    f16* wau11h = (f16*)alloc(16384); f16* wbu11h = (f16*)alloc(16384); f16* wcu11h = (f16*)alloc(16384);
    f16* wau12h = (f16*)alloc(4096);  f16* wbu12h = (f16*)alloc(4096);  f16* wcu12h = (f16*)alloc(4096);
    f16* wau13h = (f16*)alloc(256);   f16* wbu13h = (f16*)alloc(256);   f16* wcu13h = (f16*)alloc(256);
    f16* wr2Th  = (f16*)alloc(8192);
    f16* uwr1Th = (f16*)alloc(8192);

    // fp64 weights (encoder)
    double* wa11_64 = (double*)alloc(4096);
    double* wb11_64 = (double*)alloc(4096);
    double* wc11_64 = (double*)alloc(4096);
    double* wa13_64 = (double*)alloc(16384);
    double* wb13_64 = (double*)alloc(16384);
    double* wc13_64 = (double*)alloc(16384);
    double* wr1T_64 = (double*)alloc(8192);

    // ---- aliases ----
    f16*    CATh = (f16*)R1;
    double* H1   = (double*)R1;
    float*  D1   = R2;                       // [g][n][b][128] fp32
    float*  H2   = R2;                       // [g][q][b][192] fp32
    float*  Y3   = R2 + 4718592;             // [g][q][b][128] fp32
    float*  O    = R2;                       // final [g][n][b][8] fp32
    float*  H64  = R2 + 12582912;            // [g][n][b][64] fp32
    f16*    T1h  = (f16*)(R2 + 18874368);    // f16[6291456]
    f16*    T2h  = (f16*)(R2 + 22020096);    // f16[6291456]
    double* E1   = (double*)R2;              // dbl[12582912] spans R2
    double* XT64 = (double*)R3;
    f16*    H2h  = (f16*)R3;                 // early phase-2
    f16*    D1h  = (f16*)R3;                 // late phase-2 (H2h dead)
    double* T1d  = (double*)R4;              // dbl[3145728]: conv1 [4][3072][256] / conv2 [2][3072][512]
    double* T2d  = (double*)IDX;             // dbl[3145728] spanning IDX + L0f front half
    f16*    Ph   = (f16*)R4;                 // f16[3145728] (phase 2)
    f16*    H64h = (f16*)(R4 + 1572864);     // f16[6291456] (phase 2)
    f16*    L0h  = (f16*)L0f;
    f16*    L1h  = (f16*)L1f;
    double* ST64 = (double*)(ST + 512);

    auto gh = [&](int mode, const f16* A, const f16* B, void* C, int M, int K, int N,
                  int ldc, long long sB, long long sC, int z) {
        dim3 grid((N + 127) / 128, M / 128, z);
        if (mode == 0)      gemm_h<0><<<grid, 256, 0, stream>>>(A, B, C, M, K, N, ldc, sB, sC);
        else if (mode == 1) gemm_h<1><<<grid, 256, 0, stream>>>(A, B, C, M, K, N, ldc, sB, sC);
        else                gemm_h<2><<<grid, 256, 0, stream>>>(A, B, C, M, K, N, ldc, sB, sC);
    };
    auto gemm64f = [&](const float* A, const double* B, double* C, int M, int K, int N,
                       long long sB, long long sC, int z, int accum) {
        dim3 grid((N + 63) / 64, M / 64, z);
        gemm_f64<float><<<grid, 256, 0, stream>>>(A, B, C, M, K, N, sB, sC, accum);
    };
    auto gemm64d = [&](const double* A, const double* B, double* C, int M, int K, int N, int accum) {
        dim3 grid((N + 63) / 64, M / 64);
        gemm_f64<double><<<grid, 256, 0, stream>>>(A, B, C, M, K, N, 0, 0, accum);
    };
    auto bn = [&](float* X, int rows, int C, int ld, int offc,
                  const float* gp, const float* bep, const float* rbias, f16* mirror) {
        zero_k<<<2, 256, 0, stream>>>(ST, 512);
        bn_reduce_k<<<384, C, 0, stream>>>(X, ST, rows, ld, offc);
        int total = rows * C;
        bn_apply_k<<<(total + 255) / 256, 256, 0, stream>>>(
            X, ST, gp, bep, rbias, mirror, total, C, 1.f / (float)rows, ld, offc);
    };
    auto bn64 = [&](double* X, int rows, int C,
                    const float* gp, const float* bep, const float* rbias) {
        zero_k<<<4, 256, 0, stream>>>(ST + 512, 1024);
        bn_reduce64_k<<<384, C, 0, stream>>>(X, ST64, rows, C);
        int total = rows * C;
        bn_apply64_k<<<(total + 255) / 256, 256, 0, stream>>>(
            X, ST64, gp, bep, rbias, total, C, 1.0 / (double)rows);
    };
    auto comb16 = [&](const float* w, f16* a, f16* b, f16* c, int n) {
        cheb_combine16_k<<<(n + 255) / 256, 256, 0, stream>>>(w, a, b, c, n);
    };

    // ---- fp64 weight prep + input regroup ----
    cheb_combine64_k<<<8, 256, 0, stream>>>(w11, wa11_64, wb11_64, wc11_64, 2048);
    cheb_combine64_k<<<32, 256, 0, stream>>>(w13, wa13_64, wb13_64, wc13_64, 8192);
    transpose_w64_k<<<16, 256, 0, stream>>>(wr1, wr1T_64, 128, 32);
    regroup_in64_k<<<12288, 256, 0, stream>>>(x, XT64, 3145728);

    // ==== PHASE 1 (fp64): encoder to e1, exact argmax ====
    // conv1: 32 -> 64, z=4 batched (T1d/T2d = [4][3072][256] dbl)
    gemm64f(L0, XT64, T1d, 3072, 3072, 256, 786432, 786432, 4, 0);
    gemm64f(L0, T1d, T2d, 3072, 3072, 256, 786432, 786432, 4, 0);
    gemm64d(XT64, wa11_64, H1, 98304, 32, 64, 0);
    gemm64d(T1d,  wb11_64, H1, 98304, 32, 64, 1);
    gemm64d(T2d,  wc11_64, H1, 98304, 32, 64, 1);
    bn64(H1, 98304, 64, g11, be11, nullptr);                 // h1

    // conv2: 64 -> 128, two z=2 halves (T1d/T2d = [2][3072][512] dbl)
    for (int h = 0; h < 2; ++h) {
        const double* Hh = H1 + (size_t)h * 3145728;
        double*       Eh = E1 + (size_t)h * 6291456;
        gemm64f(L0, Hh, T1d, 3072, 3072, 512, 1572864, 1572864, 2, 0);
        gemm64f(L0, T1d, T2d, 3072, 3072, 512, 1572864, 1572864, 2, 0);
        gemm64d(Hh,  wa13_64, Eh, 49152, 64, 128, 0);
        gemm64d(T1d, wb13_64, Eh, 49152, 64, 128, 1);
        gemm64d(T2d, wc13_64, Eh, 49152, 64, 128, 1);
    }
    bn64(E1, 98304, 128, g13, be13, br1);
    gemm64d(XT64, wr1T_64, E1, 98304, 32, 128, 1);           // e1 (fp64)

    // ---- f16 weight prep (delayed: L0f/IDX regions were phase-1 scratch) ----
    comb16(w21,  wa21h,  wb21h,  wc21h,  24576);
    comb16(w23,  wa23h,  wb23h,  wc23h,  24576);
    comb16(uw11, wau11h, wbu11h, wcu11h, 32768);
    comb16(uw12, wau12h, wbu12h, wcu12h, 8192);
    comb16(uw13, wau13h, wbu13h, wcu13h, 512);
    transpose_w16_k<<<64, 256, 0, stream>>>(wr2, wr2Th, 128, 128);
    transpose_w16_k<<<64, 256, 0, stream>>>(uwr1, uwr1Th, 64, 256);
    cast16_k<<<36864, 256, 0, stream>>>(L0, L0h, 9437184);
    cast16_k<<<2304, 256, 0, stream>>>(L1, L1h, 589824);

    // transition: pool on fp64; CATh high = f16(e1)
    pool4_64_k<<<12288, 256, 0, stream>>>(E1, Ph, IDX, 3145728);
    cast_e1_k<<<49152, 256, 0, stream>>>(E1, CATh, 12582912);
    // E1 / XT64 / H1 / T1d / T2d dead from here.

    // ==== PHASE 2 (fp16 MFMA) ====
    // L2 conv1: 128 -> 192
    gh(0, L1h, Ph, T1h, 768, 768, 1024, 1024, 786432, 786432, 4);
    gh(0, L1h, T1h, T2h, 768, 768, 1024, 1024, 786432, 786432, 4);
    gh(1, Ph,  wa21h, H2, 24576, 128, 192, 192, 0, 0, 1);
    gh(2, T1h, wb21h, H2, 24576, 128, 192, 192, 0, 0, 1);
    gh(2, T2h, wc21h, H2, 24576, 128, 192, 192, 0, 0, 1);
    bn(H2, 24576, 192, 192, 0, g21, be21, nullptr, H2h);     // h2 (+f16 mirror)

    // L2 conv2: 192 -> 128, + residual -> e2 (Y3)
    gh(0, L1h, H2h, T1h, 768, 768, 1536, 1536, 1179648, 1179648, 4);
    gh(0, L1h, T1h, T2h, 768, 768, 1536, 1536, 1179648, 1179648, 4);
    gh(1, H2h, wa23h, Y3, 24576, 192, 128, 128, 0, 0, 1);
    gh(2, T1h, wb23h, Y3, 24576, 192, 128, 128, 0, 0, 1);
    gh(2, T2h, wc23h, Y3, 24576, 192, 128, 128, 0, 0, 1);
    bn(Y3, 24576, 128, 128, 0, g23, be23, br2, nullptr);
    gh(2, Ph, wr2Th, Y3, 24576, 128, 128, 128, 0, 0, 1);     // e2

    // unpool into CATh low (f16)
    unpool_cat_k<<<12288, 256, 0, stream>>>(Y3, IDX, CATh, 3145728);

    // dec conv1: 256 -> 128 (per group)
    for (int g = 0; g < 4; ++g) {
        const f16* Bg = CATh + (size_t)g * 6291456;
        float* Dg = D1 + (size_t)g * 3145728;
        gh(0, L0h, Bg, T1h, 3072, 3072, 2048, 2048, 0, 0, 1);
        gh(0, L0h, T1h, T2h, 3072, 3072, 2048, 2048, 0, 0, 1);
        gh(1, Bg,  wau11h, Dg, 24576, 256, 128, 128, 0, 0, 1);
        gh(2, T1h, wbu11h, Dg, 24576, 256, 128, 128, 0, 0, 1);
        gh(2, T2h, wcu11h, Dg, 24576, 256, 128, 128, 0, 0, 1);
    }
    bn(D1, 98304, 128, 128, 0, ug11, ube11, nullptr, D1h);   // d1 (+f16 mirror)

    // dec conv2: 128 -> 64, + residual from cat
    for (int g = 0; g < 4; ++g) {
        const f16* Bg = D1h + (size_t)g * 3145728;           // 128-ch group stride
        float* Dg = H64 + (size_t)g * 1572864;
        gh(0, L0h, Bg, T1h, 3072, 3072, 1024, 1024, 0, 0, 1);
        gh(0, L0h, T1h, T2h, 3072, 3072, 1024, 1024, 0, 0, 1);
        gh(1, Bg,  wau12h, Dg, 24576, 128, 64, 64, 0, 0, 1);
        gh(2, T1h, wbu12h, Dg, 24576, 128, 64, 64, 0, 0, 1);
        gh(2, T2h, wcu12h, Dg, 24576, 128, 64, 64, 0, 0, 1);
    }
    bn(H64, 98304, 64, 64, 0, ug12, ube12, ubr1, nullptr);
    gh(2, CATh, uwr1Th, H64, 98304, 256, 64, 64, 0, 0, 1);   // d2 = bn + residual
    cast16_k<<<24576, 256, 0, stream>>>(H64, H64h, 6291456); // d2 f16 mirror

    // final conv: 64 -> 8
    gh(0, L0h, H64h, T1h, 3072, 3072, 512, 512, 1572864, 1572864, 4);
    gh(0, L0h, T1h, T2h, 3072, 3072, 512, 512, 1572864, 1572864, 4);
    gh(1, H64h, wau13h, O, 98304, 64, 8, 8, 0, 0, 1);
    gh(2, T1h,  wbu13h, O, 98304, 64, 8, 8, 0, 0, 1);
    gh(2, T2h,  wcu13h, O, 98304, 64, 8, 8, 0, 0, 1);

    transpose_out_k<<<3072, 256, 0, stream>>>(O, ub13, out, 786432);
}

// Round 7
// 6237.656 us; speedup vs baseline: 2.7136x; 1.1090x over previous
//
#include <hip/hip_runtime.h>

typedef _Float16 f16;
typedef f16   half8 __attribute__((ext_vector_type(8)));
typedef float f32x4 __attribute__((ext_vector_type(4)));

#define LDH 40   // padded halves per LDS row (16B-aligned rows, conflict-reducing)

// ---------------------------------------------------------------------------
// fp16 MFMA GEMM with k+1 register prefetch. C[M,N] = A[M,K]*B[K,N].
// MODE 0: f16 store; 1: f32 store; 2: f32 accumulate-add.
// blockIdx.z batches B/C by sB/sC. M%128==0, K%32==0, N%8==0.
// ---------------------------------------------------------------------------
template <int MODE>
__global__ __launch_bounds__(256) void gemm_h(
    const f16* __restrict__ A, const f16* __restrict__ Bg, void* __restrict__ Cg,
    int M, int K, int N, int ldc, long long sB, long long sC)
{
    const f16* B = Bg + (size_t)blockIdx.z * sB;

    __shared__ f16 Ah[128][LDH];
    __shared__ f16 Bt[128][LDH];   // B transposed: Bt[n][k ^ swz(n)]

    const int tid  = threadIdx.x;
    const int lane = tid & 63;
    const int wv   = tid >> 6;
    const int wm   = wv >> 1, wn = wv & 1;
    const int ln   = lane & 15;
    const int q    = lane >> 4;

    const int row0 = blockIdx.y * 128;
    const int col0 = blockIdx.x * 128;

    const int am = tid >> 1;           // A-stage row 0..127
    const int ak = (tid & 1) << 4;     // A-stage k 0/16
    const int bk = tid >> 3;           // B-stage k 0..31
    const int bn = (tid & 7) << 4;     // B-stage col 0..112

    const f16* Arow = A + (size_t)(row0 + am) * K + ak;
    const int  cb   = col0 + bn;

    f32x4 acc[4][4];
#pragma unroll
    for (int i = 0; i < 4; ++i)
#pragma unroll
        for (int j = 0; j < 4; ++j) acc[i][j] = (f32x4){0.f, 0.f, 0.f, 0.f};

    // prologue loads (k0 = 0)
    uint4 a0 = *(const uint4*)(Arow);
    uint4 a1 = *(const uint4*)(Arow + 8);
    uint4 b0 = make_uint4(0, 0, 0, 0), b1 = make_uint4(0, 0, 0, 0);
    {
        const f16* Brow = B + (size_t)bk * N;
        if (cb + 8  <= N) b0 = *(const uint4*)(Brow + cb);
        if (cb + 16 <= N) b1 = *(const uint4*)(Brow + cb + 8);
    }

    for (int k0 = 0; k0 < K; k0 += 32) {
        __syncthreads();
        *(uint4*)&Ah[am][ak]     = a0;
        *(uint4*)&Ah[am][ak + 8] = a1;
        {
            const f16* h0 = (const f16*)&b0;
            const f16* h1 = (const f16*)&b1;
#pragma unroll
            for (int j = 0; j < 8; ++j) {
                int n = bn + j;
                Bt[n][bk ^ (((n >> 4) & 3) << 3)] = h0[j];
            }
#pragma unroll
            for (int j = 0; j < 8; ++j) {
                int n = bn + 8 + j;
                Bt[n][bk ^ (((n >> 4) & 3) << 3)] = h1[j];
            }
        }
        __syncthreads();

        // prefetch k0+32 (overlaps the MFMA block below)
        if (k0 + 32 < K) {
            a0 = *(const uint4*)(Arow + k0 + 32);
            a1 = *(const uint4*)(Arow + k0 + 40);
            const f16* Brow = B + (size_t)(k0 + 32 + bk) * N;
            if (cb + 8  <= N) b0 = *(const uint4*)(Brow + cb);
            if (cb + 16 <= N) b1 = *(const uint4*)(Brow + cb + 8);
        }

        half8 af[4], bf[4];
#pragma unroll
        for (int i = 0; i < 4; ++i)
            af[i] = *(const half8*)&Ah[wm * 64 + i * 16 + ln][q * 8];
#pragma unroll
        for (int j = 0; j < 4; ++j) {
            const int nb = wn * 64 + j * 16 + ln;
            const int sw = ((wn * 4 + j) & 3) << 3;
            bf[j] = *(const half8*)&Bt[nb][(q * 8) ^ sw];
        }
#pragma unroll
        for (int i = 0; i < 4; ++i)
#pragma unroll
            for (int j = 0; j < 4; ++j)
                acc[i][j] = __builtin_amdgcn_mfma_f32_16x16x32_f16(af[i], bf[j], acc[i][j], 0, 0, 0);
    }

    const size_t zoff = (size_t)blockIdx.z * sC;
#pragma unroll
    for (int i = 0; i < 4; ++i) {
#pragma unroll
        for (int j = 0; j < 4; ++j) {
            const int c = col0 + wn * 64 + j * 16 + ln;
            if (c < N) {
#pragma unroll
                for (int t = 0; t < 4; ++t) {
                    const int r = row0 + wm * 64 + i * 16 + q * 4 + t;
                    const size_t o = zoff + (size_t)r * ldc + c;
                    const float v = acc[i][j][t];
                    if (MODE == 0)      ((f16*)Cg)[o] = (f16)v;
                    else if (MODE == 1) ((float*)Cg)[o] = v;
                    else                ((float*)Cg)[o] += v;
                }
            }
        }
    }
}

// ---------------------------------------------------------------------------
// fp64 GEMM (pool-argmax-critical path). TILE 64, BK 16, 256 thr, 4x4 micro.
// Stride-66 LDS rows (bank = 4k+2c: staging writes <=2-way, 16B-aligned rows).
// Micro col = tx + 16*j (reads broadcast, C stores contiguous). Register
// prefetch of the next k-tile overlaps the FMA block.
// ---------------------------------------------------------------------------
#define LDD 66

__device__ inline void loadA4(const float* p, double* d) {
    float4 v = *(const float4*)p;
    d[0] = v.x; d[1] = v.y; d[2] = v.z; d[3] = v.w;
}
__device__ inline void loadA4(const double* p, double* d) {
    double2 v0 = *(const double2*)p, v1 = *(const double2*)(p + 2);
    d[0] = v0.x; d[1] = v0.y; d[2] = v1.x; d[3] = v1.y;
}

template <typename TA>
__global__ __launch_bounds__(256) void gemm_f64(
    const TA* __restrict__ A, const double* __restrict__ Bg, double* __restrict__ Cg,
    int M, int K, int N, long long sB, long long sC, int accum)
{
    const double* B = Bg + (size_t)blockIdx.z * sB;
    double*       C = Cg + (size_t)blockIdx.z * sC;

    __shared__ double As[16][LDD];
    __shared__ double Bs[16][LDD];

    const int tid  = threadIdx.x;
    const int tx   = tid & 15;
    const int ty   = tid >> 4;
    const int row0 = blockIdx.y * 64;
    const int col0 = blockIdx.x * 64;

    const int ra = tid >> 2;
    const int ka = (tid & 3) << 2;
    const int kb = tid >> 4;
    const int cb = (tid & 15) << 2;

    const TA* Arow = A + (size_t)(row0 + ra) * K + ka;
    const int cbase = col0 + cb;

    double acc[4][4];
#pragma unroll
    for (int i = 0; i < 4; ++i)
#pragma unroll
        for (int j = 0; j < 4; ++j) acc[i][j] = 0.0;

    // prologue loads (k0 = 0)
    double av[4];
    double2 bv0 = {0.0, 0.0}, bv1 = {0.0, 0.0};
    loadA4(Arow, av);
    if (cbase < N) {
        bv0 = *(const double2*)(B + (size_t)kb * N + cbase);
        bv1 = *(const double2*)(B + (size_t)kb * N + cbase + 2);
    }

    for (int k0 = 0; k0 < K; k0 += 16) {
        __syncthreads();
        As[ka + 0][ra] = av[0]; As[ka + 1][ra] = av[1];
        As[ka + 2][ra] = av[2]; As[ka + 3][ra] = av[3];
        *(double2*)&Bs[kb][cb]     = bv0;
        *(double2*)&Bs[kb][cb + 2] = bv1;
        __syncthreads();

        // prefetch k0+16 (overlaps FMA block)
        if (k0 + 16 < K) {
            loadA4(Arow + k0 + 16, av);
            if (cbase < N) {
                bv0 = *(const double2*)(B + (size_t)(k0 + 16 + kb) * N + cbase);
                bv1 = *(const double2*)(B + (size_t)(k0 + 16 + kb) * N + cbase + 2);
            }
        }

#pragma unroll
        for (int kk = 0; kk < 16; ++kk) {
            const double2* pa = (const double2*)&As[kk][ty << 2];
            const double2 a01 = pa[0], a23 = pa[1];
            double ar[4], br[4];
            ar[0] = a01.x; ar[1] = a01.y; ar[2] = a23.x; ar[3] = a23.y;
            br[0] = Bs[kk][tx];      br[1] = Bs[kk][tx + 16];
            br[2] = Bs[kk][tx + 32]; br[3] = Bs[kk][tx + 48];
#pragma unroll
            for (int i = 0; i < 4; ++i)
#pragma unroll
                for (int j = 0; j < 4; ++j)
                    acc[i][j] = fma(ar[i], br[j], acc[i][j]);
        }
    }

#pragma unroll
    for (int i = 0; i < 4; ++i) {
        const int r = row0 + (ty << 2) + i;
#pragma unroll
        for (int j = 0; j < 4; ++j) {
            const int c = col0 + tx + 16 * j;
            if (c < N) {
                double* p = C + (size_t)r * N + c;
                double v = acc[i][j];
                if (accum) v += *p;
                *p = v;
            }
        }
    }
}

// ---------------------------------------------------------------------------
// Aux kernels. Activation layout: [g=4][node][b=8][C].
// ---------------------------------------------------------------------------
__global__ void zero_k(float* __restrict__ p, int n) {
    int i = blockIdx.x * blockDim.x + threadIdx.x;
    if (i < n) p[i] = 0.f;
}

__global__ void cast16_k(const float* __restrict__ s, f16* __restrict__ d, int n) {
    int i = blockIdx.x * blockDim.x + threadIdx.x;
    if (i < n) d[i] = (f16)s[i];
}

// x [32][3072][32] fp32 -> XT64 [g][n][bi][32] fp64
__global__ void regroup_in64_k(const float* __restrict__ x, double* __restrict__ XT, int total) {
    int i = blockIdx.x * blockDim.x + threadIdx.x;
    if (i >= total) return;
    int c = i & 31;
    int t = i >> 5;
    int n = t % 3072;
    int b = t / 3072;
    XT[((((size_t)(b >> 3) * 3072 + n) << 3) + (b & 7)) * 32 + c] = (double)x[i];
}

// fp16 combine: wa=w0-w2, wb=w1, wc=2*w2
__global__ void cheb_combine16_k(const float* __restrict__ w, f16* __restrict__ wa,
                                 f16* __restrict__ wb, f16* __restrict__ wc, int n) {
    int i = blockIdx.x * blockDim.x + threadIdx.x;
    if (i >= n) return;
    float w0 = w[i], w1 = w[n + i], w2 = w[2 * n + i];
    wa[i] = (f16)(w0 - w2); wb[i] = (f16)w1; wc[i] = (f16)(2.f * w2);
}
// fp64 combine (encoder)
__global__ void cheb_combine64_k(const float* __restrict__ w, double* __restrict__ wa,
                                 double* __restrict__ wb, double* __restrict__ wc, int n) {
    int i = blockIdx.x * blockDim.x + threadIdx.x;
    if (i >= n) return;
    double w0 = w[i], w1 = w[n + i], w2 = w[2 * n + i];
    wa[i] = w0 - w2; wb[i] = w1; wc[i] = 2.0 * w2;
}

__global__ void transpose_w16_k(const float* __restrict__ w, f16* __restrict__ wt, int R, int Ccol) {
    int i = blockIdx.x * blockDim.x + threadIdx.x;
    if (i >= R * Ccol) return;
    int r = i / Ccol, c = i - r * Ccol;
    wt[(size_t)c * R + r] = (f16)w[i];
}
__global__ void transpose_w64_k(const float* __restrict__ w, double* __restrict__ wt, int R, int Ccol) {
    int i = blockIdx.x * blockDim.x + threadIdx.x;
    if (i >= R * Ccol) return;
    int r = i / Ccol, c = i - r * Ccol;
    wt[(size_t)c * R + r] = (double)w[i];
}

// fp32 BN (stats; apply in-place + optional f16 mirror)
__global__ void bn_reduce_k(const float* __restrict__ X, float* __restrict__ stats,
                            int rows, int ld, int off) {
    int c = threadIdx.x;
    float s = 0.f, s2 = 0.f;
    for (int r = blockIdx.x; r < rows; r += gridDim.x) {
        float v = X[(size_t)r * ld + off + c];
        s += v; s2 += v * v;
    }
    atomicAdd(&stats[c], s);
    atomicAdd(&stats[256 + c], s2);
}
__global__ void bn_apply_k(float* X, const float* __restrict__ stats,
                           const float* __restrict__ g, const float* __restrict__ be,
                           const float* rbias, f16* mirror,
                           int total, int C, float invN, int ld, int off) {
    int i = blockIdx.x * blockDim.x + threadIdx.x;
    if (i >= total) return;
    int c = i % C;
    int row = i / C;
    size_t a = (size_t)row * ld + off + c;
    float mu = stats[c] * invN;
    float var = stats[256 + c] * invN - mu * mu;
    float sc = g[c] * rsqrtf(var + 1e-5f);
    float v = (X[a] - mu) * sc + be[c];
    v = fmaxf(v, 0.f);
    if (rbias) v += rbias[c];
    X[a] = v;
    if (mirror) mirror[a] = (f16)v;
}

// fp64 BN (encoder)
__global__ void bn_reduce64_k(const double* __restrict__ X, double* __restrict__ stats,
                              int rows, int ld) {
    int c = threadIdx.x;
    double s = 0.0, s2 = 0.0;
    for (int r = blockIdx.x; r < rows; r += gridDim.x) {
        double v = X[(size_t)r * ld + c];
        s += v; s2 += v * v;
    }
    atomicAdd(&stats[c], s);
    atomicAdd(&stats[256 + c], s2);
}
__global__ void bn_apply64_k(double* X, const double* __restrict__ stats,
                             const float* __restrict__ g, const float* __restrict__ be,
                             const float* rbias, int total, int C, double invN) {
    int i = blockIdx.x * blockDim.x + threadIdx.x;
    if (i >= total) return;
    int c = i % C;
    double mu = stats[c] * invN;
    double var = stats[256 + c] * invN - mu * mu;
    double sc = (double)g[c] / sqrt(var + 1e-5);
    double v = (X[i] - mu) * sc + (double)be[c];
    v = v > 0.0 ? v : 0.0;
    if (rbias) v += (double)rbias[c];
    X[i] = v;
}

// fp64 e1 [row][128] -> CATh high half (f16, ld 256, off 128)
__global__ void cast_e1_k(const double* __restrict__ E1, f16* __restrict__ cat, int total) {
    int i = blockIdx.x * blockDim.x + threadIdx.x;
    if (i >= total) return;
    int c = i & 127;
    int row = i >> 7;
    cat[(size_t)row * 256 + 128 + c] = (f16)E1[i];
}

// pool 4 consecutive nodes of fp64 e1 -> Ph f16 [g][q][b][128], IDX node index
__global__ void pool4_64_k(const double* __restrict__ e1, f16* __restrict__ p,
                           int* __restrict__ idx, int total) {
    int i = blockIdx.x * blockDim.x + threadIdx.x;
    if (i >= total) return;
    int c = i & 127;
    int t = i >> 7;
    int b = t & 7;
    t >>= 3;
    int q = t % 768;
    int g = t / 768;
    size_t base = ((((size_t)g * 3072 + 4 * q) << 3) + b) * 128 + c;
    double best = e1[base];
    int bj = 0;
#pragma unroll
    for (int j = 1; j < 4; ++j) {
        double v = e1[base + (size_t)j * 1024];
        if (v > best) { best = v; bj = j; }   // strict >: first occurrence (jnp.argmax)
    }
    p[i] = (f16)best;
    idx[i] = 4 * q + bj;
}

// scatter e2 (fp32) into CATh low half (f16)
__global__ void unpool_cat_k(const float* __restrict__ e2, const int* __restrict__ idx,
                             f16* __restrict__ cat, int total) {
    int i = blockIdx.x * blockDim.x + threadIdx.x;
    if (i >= total) return;
    int c = i & 127;
    int t = i >> 7;
    int b = t & 7;
    t >>= 3;
    int q = t % 768;
    int g = t / 768;
    f16 val = (f16)e2[i];
    int id = idx[i];
    size_t base = ((((size_t)g * 3072 + 4 * q) << 3) + b) * 256 + c;
#pragma unroll
    for (int j = 0; j < 4; ++j)
        cat[base + (size_t)j * 2048] = (4 * q + j == id) ? val : (f16)0.f;
}

// O [g][n][bi][8] fp32 -> out [B][N][8], + bias
__global__ void transpose_out_k(const float* __restrict__ O, const float* __restrict__ bias,
                                float* __restrict__ out, int total) {
    int i = blockIdx.x * blockDim.x + threadIdx.x;
    if (i >= total) return;
    int c = i & 7;
    int t = i >> 3;
    int n = t % 3072;
    int b = t / 3072;
    out[i] = O[((((size_t)(b >> 3) * 3072 + n) << 3) + (b & 7)) * 8 + c] + bias[c];
}

// ---------------------------------------------------------------------------
extern "C" void kernel_launch(void* const* d_in, const int* in_sizes, int n_in,
                              void* d_out, int out_size, void* d_ws, size_t ws_size,
                              hipStream_t stream)
{
    (void)in_sizes; (void)n_in; (void)out_size; (void)ws_size;

    const float* x    = (const float*)d_in[0];
    const float* L0   = (const float*)d_in[1];
    const float* L1   = (const float*)d_in[2];
    const float* w11  = (const float*)d_in[3];
    const float* g11  = (const float*)d_in[5];
    const float* be11 = (const float*)d_in[6];
    const float* w13  = (const float*)d_in[7];
    const float* g13  = (const float*)d_in[9];
    const float* be13 = (const float*)d_in[10];
    const float* wr1  = (const float*)d_in[11];
    const float* br1  = (const float*)d_in[12];
    const float* w21  = (const float*)d_in[13];
    const float* g21  = (const float*)d_in[15];
    const float* be21 = (const float*)d_in[16];
    const float* w23  = (const float*)d_in[17];
    const float* g23  = (const float*)d_in[19];
    const float* be23 = (const float*)d_in[20];
    const float* wr2  = (const float*)d_in[21];
    const float* br2  = (const float*)d_in[22];
    const float* uw11 = (const float*)d_in[23];
    const float* ug11 = (const float*)d_in[25];
    const float* ube11= (const float*)d_in[26];
    const float* uw12 = (const float*)d_in[27];
    const float* ug12 = (const float*)d_in[29];
    const float* ube12= (const float*)d_in[30];
    const float* uwr1 = (const float*)d_in[31];
    const float* ubr1 = (const float*)d_in[32];
    const float* uw13 = (const float*)d_in[33];
    const float* ub13 = (const float*)d_in[34];
    float* out = (float*)d_out;

    float* ws = (float*)d_ws;
    size_t off = 0;
    auto alloc = [&](size_t n) { float* p = ws + off; off += (n + 63) & ~(size_t)63; return p; };

    // ---- regions (floats). Total ~224 MiB. ----
    float* R1 = alloc(12582912);   // CATh f16[25165824] | p1: H1 dbl[6291456]
    float* R2 = alloc(25165824);   // D1 fp32 + H64 fp32 + T1h/T2h f16 | p1: E1 dbl[12582912]
    float* R3 = alloc(6291456);    // p1: XT64 dbl[3145728] | p2: H2h f16 then D1h f16
    float* R4 = alloc(6291456);    // p1: T1d dbl[3145728] | p2: Ph f16 + H64h f16
    int*  IDX = (int*)alloc(3145728);  // p1 (with L0f): T2d dbl[3145728]
    float* L0f = alloc(4718592);   // p2: L0h f16[9437184]
    float* L1f = alloc(294912);    // p2: L1h f16[589824]
    float* ST  = alloc(1536);      // fp32 stats [0..512), fp64 stats [512..1536)

    // f16 weights
    f16* wa21h = (f16*)alloc(12288); f16* wb21h = (f16*)alloc(12288); f16* wc21h = (f16*)alloc(12288);
    f16* wa23h = (f16*)alloc(12288); f16* wb23h = (f16*)alloc(12288); f16* wc23h = (f16*)alloc(12288);
    f16* wau11h = (f16*)alloc(16384); f16* wbu11h = (f16*)alloc(16384); f16* wcu11h = (f16*)alloc(16384);
    f16* wau12h = (f16*)alloc(4096);  f16* wbu12h = (f16*)alloc(4096);  f16* wcu12h = (f16*)alloc(4096);
    f16* wau13h = (f16*)alloc(256);   f16* wbu13h = (f16*)alloc(256);   f16* wcu13h = (f16*)alloc(256);
    f16* wr2Th  = (f16*)alloc(8192);
    f16* uwr1Th = (f16*)alloc(8192);

    // fp64 weights (encoder)
    double* wa11_64 = (double*)alloc(4096);
    double* wb11_64 = (double*)alloc(4096);
    double* wc11_64 = (double*)alloc(4096);
    double* wa13_64 = (double*)alloc(16384);
    double* wb13_64 = (double*)alloc(16384);
    double* wc13_64 = (double*)alloc(16384);
    double* wr1T_64 = (double*)alloc(8192);

    // ---- aliases ----
    f16*    CATh = (f16*)R1;
    double* H1   = (double*)R1;
    float*  D1   = R2;                       // [g][n][b][128] fp32
    float*  H2   = R2;                       // [g][q][b][192] fp32
    float*  Y3   = R2 + 4718592;             // [g][q][b][128] fp32
    float*  O    = R2;                       // final [g][n][b][8] fp32
    float*  H64  = R2 + 12582912;            // [g][n][b][64] fp32
    f16*    T1h  = (f16*)(R2 + 18874368);    // f16[6291456]
    f16*    T2h  = (f16*)(R2 + 22020096);    // f16[6291456]
    double* E1   = (double*)R2;              // dbl[12582912] spans R2
    double* XT64 = (double*)R3;
    f16*    H2h  = (f16*)R3;                 // early phase-2
    f16*    D1h  = (f16*)R3;                 // late phase-2 (H2h dead)
    double* T1d  = (double*)R4;              // dbl[3145728]
    double* T2d  = (double*)IDX;             // dbl[3145728] spanning IDX + L0f front half
    f16*    Ph   = (f16*)R4;                 // f16[3145728] (phase 2)
    f16*    H64h = (f16*)(R4 + 1572864);     // f16[6291456] (phase 2)
    f16*    L0h  = (f16*)L0f;
    f16*    L1h  = (f16*)L1f;
    double* ST64 = (double*)(ST + 512);

    auto gh = [&](int mode, const f16* A, const f16* B, void* C, int M, int K, int N,
                  int ldc, long long sB, long long sC, int z) {
        dim3 grid((N + 127) / 128, M / 128, z);
        if (mode == 0)      gemm_h<0><<<grid, 256, 0, stream>>>(A, B, C, M, K, N, ldc, sB, sC);
        else if (mode == 1) gemm_h<1><<<grid, 256, 0, stream>>>(A, B, C, M, K, N, ldc, sB, sC);
        else                gemm_h<2><<<grid, 256, 0, stream>>>(A, B, C, M, K, N, ldc, sB, sC);
    };
    auto gemm64f = [&](const float* A, const double* B, double* C, int M, int K, int N,
                       long long sB, long long sC, int z, int accum) {
        dim3 grid((N + 63) / 64, M / 64, z);
        gemm_f64<float><<<grid, 256, 0, stream>>>(A, B, C, M, K, N, sB, sC, accum);
    };
    auto gemm64d = [&](const double* A, const double* B, double* C, int M, int K, int N, int accum) {
        dim3 grid((N + 63) / 64, M / 64);
        gemm_f64<double><<<grid, 256, 0, stream>>>(A, B, C, M, K, N, 0, 0, accum);
    };
    auto bn = [&](float* X, int rows, int C, int ld, int offc,
                  const float* gp, const float* bep, const float* rbias, f16* mirror) {
        zero_k<<<2, 256, 0, stream>>>(ST, 512);
        bn_reduce_k<<<384, C, 0, stream>>>(X, ST, rows, ld, offc);
        int total = rows * C;
        bn_apply_k<<<(total + 255) / 256, 256, 0, stream>>>(
            X, ST, gp, bep, rbias, mirror, total, C, 1.f / (float)rows, ld, offc);
    };
    auto bn64 = [&](double* X, int rows, int C,
                    const float* gp, const float* bep, const float* rbias) {
        zero_k<<<4, 256, 0, stream>>>(ST + 512, 1024);
        bn_reduce64_k<<<384, C, 0, stream>>>(X, ST64, rows, C);
        int total = rows * C;
        bn_apply64_k<<<(total + 255) / 256, 256, 0, stream>>>(
            X, ST64, gp, bep, rbias, total, C, 1.0 / (double)rows);
    };
    auto comb16 = [&](const float* w, f16* a, f16* b, f16* c, int n) {
        cheb_combine16_k<<<(n + 255) / 256, 256, 0, stream>>>(w, a, b, c, n);
    };

    // ---- fp64 weight prep + input regroup ----
    cheb_combine64_k<<<8, 256, 0, stream>>>(w11, wa11_64, wb11_64, wc11_64, 2048);
    cheb_combine64_k<<<32, 256, 0, stream>>>(w13, wa13_64, wb13_64, wc13_64, 8192);
    transpose_w64_k<<<16, 256, 0, stream>>>(wr1, wr1T_64, 128, 32);
    regroup_in64_k<<<12288, 256, 0, stream>>>(x, XT64, 3145728);

    // ==== PHASE 1 (fp64): encoder to e1, exact argmax ====
    // conv1: 32 -> 64, z=4 batched (T1d/T2d = [4][3072][256] dbl)
    gemm64f(L0, XT64, T1d, 3072, 3072, 256, 786432, 786432, 4, 0);
    gemm64f(L0, T1d, T2d, 3072, 3072, 256, 786432, 786432, 4, 0);
    gemm64d(XT64, wa11_64, H1, 98304, 32, 64, 0);
    gemm64d(T1d,  wb11_64, H1, 98304, 32, 64, 1);
    gemm64d(T2d,  wc11_64, H1, 98304, 32, 64, 1);
    bn64(H1, 98304, 64, g11, be11, nullptr);                 // h1

    // conv2: 64 -> 128, two z=2 halves (T1d/T2d = [2][3072][512] dbl)
    for (int h = 0; h < 2; ++h) {
        const double* Hh = H1 + (size_t)h * 3145728;
        double*       Eh = E1 + (size_t)h * 6291456;
        gemm64f(L0, Hh, T1d, 3072, 3072, 512, 1572864, 1572864, 2, 0);
        gemm64f(L0, T1d, T2d, 3072, 3072, 512, 1572864, 1572864, 2, 0);
        gemm64d(Hh,  wa13_64, Eh, 49152, 64, 128, 0);
        gemm64d(T1d, wb13_64, Eh, 49152, 64, 128, 1);
        gemm64d(T2d, wc13_64, Eh, 49152, 64, 128, 1);
    }
    bn64(E1, 98304, 128, g13, be13, br1);
    gemm64d(XT64, wr1T_64, E1, 98304, 32, 128, 1);           // e1 (fp64)

    // ---- f16 weight prep (delayed: L0f/IDX regions were phase-1 scratch) ----
    comb16(w21,  wa21h,  wb21h,  wc21h,  24576);
    comb16(w23,  wa23h,  wb23h,  wc23h,  24576);
    comb16(uw11, wau11h, wbu11h, wcu11h, 32768);
    comb16(uw12, wau12h, wbu12h, wcu12h, 8192);
    comb16(uw13, wau13h, wbu13h, wcu13h, 512);
    transpose_w16_k<<<64, 256, 0, stream>>>(wr2, wr2Th, 128, 128);
    transpose_w16_k<<<64, 256, 0, stream>>>(uwr1, uwr1Th, 64, 256);
    cast16_k<<<36864, 256, 0, stream>>>(L0, L0h, 9437184);
    cast16_k<<<2304, 256, 0, stream>>>(L1, L1h, 589824);

    // transition: pool on fp64; CATh high = f16(e1)
    pool4_64_k<<<12288, 256, 0, stream>>>(E1, Ph, IDX, 3145728);
    cast_e1_k<<<49152, 256, 0, stream>>>(E1, CATh, 12582912);
    // E1 / XT64 / H1 / T1d / T2d dead from here.

    // ==== PHASE 2 (fp16 MFMA) ====
    // L2 conv1: 128 -> 192
    gh(0, L1h, Ph, T1h, 768, 768, 1024, 1024, 786432, 786432, 4);
    gh(0, L1h, T1h, T2h, 768, 768, 1024, 1024, 786432, 786432, 4);
    gh(1, Ph,  wa21h, H2, 24576, 128, 192, 192, 0, 0, 1);
    gh(2, T1h, wb21h, H2, 24576, 128, 192, 192, 0, 0, 1);
    gh(2, T2h, wc21h, H2, 24576, 128, 192, 192, 0, 0, 1);
    bn(H2, 24576, 192, 192, 0, g21, be21, nullptr, H2h);     // h2 (+f16 mirror)

    // L2 conv2: 192 -> 128, + residual -> e2 (Y3)
    gh(0, L1h, H2h, T1h, 768, 768, 1536, 1536, 1179648, 1179648, 4);
    gh(0, L1h, T1h, T2h, 768, 768, 1536, 1536, 1179648, 1179648, 4);
    gh(1, H2h, wa23h, Y3, 24576, 192, 128, 128, 0, 0, 1);
    gh(2, T1h, wb23h, Y3, 24576, 192, 128, 128, 0, 0, 1);
    gh(2, T2h, wc23h, Y3, 24576, 192, 128, 128, 0, 0, 1);
    bn(Y3, 24576, 128, 128, 0, g23, be23, br2, nullptr);
    gh(2, Ph, wr2Th, Y3, 24576, 128, 128, 128, 0, 0, 1);     // e2

    // unpool into CATh low (f16)
    unpool_cat_k<<<12288, 256, 0, stream>>>(Y3, IDX, CATh, 3145728);

    // dec conv1: 256 -> 128 (per group)
    for (int g = 0; g < 4; ++g) {
        const f16* Bg = CATh + (size_t)g * 6291456;
        float* Dg = D1 + (size_t)g * 3145728;
        gh(0, L0h, Bg, T1h, 3072, 3072, 2048, 2048, 0, 0, 1);
        gh(0, L0h, T1h, T2h, 3072, 3072, 2048, 2048, 0, 0, 1);
        gh(1, Bg,  wau11h, Dg, 24576, 256, 128, 128, 0, 0, 1);
        gh(2, T1h, wbu11h, Dg, 24576, 256, 128, 128, 0, 0, 1);
        gh(2, T2h, wcu11h, Dg, 24576, 256, 128, 128, 0, 0, 1);
    }
    bn(D1, 98304, 128, 128, 0, ug11, ube11, nullptr, D1h);   // d1 (+f16 mirror)

    // dec conv2: 128 -> 64, + residual from cat
    for (int g = 0; g < 4; ++g) {
        const f16* Bg = D1h + (size_t)g * 3145728;           // 128-ch group stride
        float* Dg = H64 + (size_t)g * 1572864;
        gh(0, L0h, Bg, T1h, 3072, 3072, 1024, 1024, 0, 0, 1);
        gh(0, L0h, T1h, T2h, 3072, 3072, 1024, 1024, 0, 0, 1);
        gh(1, Bg,  wau12h, Dg, 24576, 128, 64, 64, 0, 0, 1);
        gh(2, T1h, wbu12h, Dg, 24576, 128, 64, 64, 0, 0, 1);
        gh(2, T2h, wcu12h, Dg, 24576, 128, 64, 64, 0, 0, 1);
    }
    bn(H64, 98304, 64, 64, 0, ug12, ube12, ubr1, nullptr);
    gh(2, CATh, uwr1Th, H64, 98304, 256, 64, 64, 0, 0, 1);   // d2 = bn + residual
    cast16_k<<<24576, 256, 0, stream>>>(H64, H64h, 6291456); // d2 f16 mirror

    // final conv: 64 -> 8
    gh(0, L0h, H64h, T1h, 3072, 3072, 512, 512, 1572864, 1572864, 4);
    gh(0, L0h, T1h, T2h, 3072, 3072, 512, 512, 1572864, 1572864, 4);
    gh(1, H64h, wau13h, O, 98304, 64, 8, 8, 0, 0, 1);
    gh(2, T1h,  wbu13h, O, 98304, 64, 8, 8, 0, 0, 1);
    gh(2, T2h,  wcu13h, O, 98304, 64, 8, 8, 0, 0, 1);

    transpose_out_k<<<3072, 256, 0, stream>>>(O, ub13, out, 786432);
}

// Round 9
// 5299.919 us; speedup vs baseline: 3.1938x; 1.1769x over previous
//
#include <hip/hip_runtime.h>

typedef _Float16 f16;
typedef f16    half8 __attribute__((ext_vector_type(8)));
typedef float  f32x4 __attribute__((ext_vector_type(4)));
typedef double f64x4 __attribute__((ext_vector_type(4)));

#define LDH 40   // padded halves per LDS row (16B-aligned rows, conflict-reducing)

// ---------------------------------------------------------------------------
// fp16 MFMA GEMM with k+1 register prefetch. C[M,N] = A[M,K]*B[K,N].
// MODE 0: f16 store; 1: f32 store; 2: f32 accumulate-add.
// blockIdx.z batches B/C by sB/sC. M%128==0, K%32==0, N%8==0.
// ---------------------------------------------------------------------------
template <int MODE>
__global__ __launch_bounds__(256) void gemm_h(
    const f16* __restrict__ A, const f16* __restrict__ Bg, void* __restrict__ Cg,
    int M, int K, int N, int ldc, long long sB, long long sC)
{
    const f16* B = Bg + (size_t)blockIdx.z * sB;

    __shared__ f16 Ah[128][LDH];
    __shared__ f16 Bt[128][LDH];   // B transposed: Bt[n][k ^ swz(n)]

    const int tid  = threadIdx.x;
    const int lane = tid & 63;
    const int wv   = tid >> 6;
    const int wm   = wv >> 1, wn = wv & 1;
    const int ln   = lane & 15;
    const int q    = lane >> 4;

    const int row0 = blockIdx.y * 128;
    const int col0 = blockIdx.x * 128;

    const int am = tid >> 1;           // A-stage row 0..127
    const int ak = (tid & 1) << 4;     // A-stage k 0/16
    const int bk = tid >> 3;           // B-stage k 0..31
    const int bn = (tid & 7) << 4;     // B-stage col 0..112

    const f16* Arow = A + (size_t)(row0 + am) * K + ak;
    const int  cb   = col0 + bn;

    f32x4 acc[4][4];
#pragma unroll
    for (int i = 0; i < 4; ++i)
#pragma unroll
        for (int j = 0; j < 4; ++j) acc[i][j] = (f32x4){0.f, 0.f, 0.f, 0.f};

    // prologue loads (k0 = 0)
    uint4 a0 = *(const uint4*)(Arow);
    uint4 a1 = *(const uint4*)(Arow + 8);
    uint4 b0 = make_uint4(0, 0, 0, 0), b1 = make_uint4(0, 0, 0, 0);
    {
        const f16* Brow = B + (size_t)bk * N;
        if (cb + 8  <= N) b0 = *(const uint4*)(Brow + cb);
        if (cb + 16 <= N) b1 = *(const uint4*)(Brow + cb + 8);
    }

    for (int k0 = 0; k0 < K; k0 += 32) {
        __syncthreads();
        *(uint4*)&Ah[am][ak]     = a0;
        *(uint4*)&Ah[am][ak + 8] = a1;
        {
            const f16* h0 = (const f16*)&b0;
            const f16* h1 = (const f16*)&b1;
#pragma unroll
            for (int j = 0; j < 8; ++j) {
                int n = bn + j;
                Bt[n][bk ^ (((n >> 4) & 3) << 3)] = h0[j];
            }
#pragma unroll
            for (int j = 0; j < 8; ++j) {
                int n = bn + 8 + j;
                Bt[n][bk ^ (((n >> 4) & 3) << 3)] = h1[j];
            }
        }
        __syncthreads();

        // prefetch k0+32 (overlaps the MFMA block below)
        if (k0 + 32 < K) {
            a0 = *(const uint4*)(Arow + k0 + 32);
            a1 = *(const uint4*)(Arow + k0 + 40);
            const f16* Brow = B + (size_t)(k0 + 32 + bk) * N;
            if (cb + 8  <= N) b0 = *(const uint4*)(Brow + cb);
            if (cb + 16 <= N) b1 = *(const uint4*)(Brow + cb + 8);
        }

        half8 af[4], bf[4];
#pragma unroll
        for (int i = 0; i < 4; ++i)
            af[i] = *(const half8*)&Ah[wm * 64 + i * 16 + ln][q * 8];
#pragma unroll
        for (int j = 0; j < 4; ++j) {
            const int nb = wn * 64 + j * 16 + ln;
            const int sw = ((wn * 4 + j) & 3) << 3;
            bf[j] = *(const half8*)&Bt[nb][(q * 8) ^ sw];
        }
#pragma unroll
        for (int i = 0; i < 4; ++i)
#pragma unroll
            for (int j = 0; j < 4; ++j)
                acc[i][j] = __builtin_amdgcn_mfma_f32_16x16x32_f16(af[i], bf[j], acc[i][j], 0, 0, 0);
    }

    const size_t zoff = (size_t)blockIdx.z * sC;
#pragma unroll
    for (int i = 0; i < 4; ++i) {
#pragma unroll
        for (int j = 0; j < 4; ++j) {
            const int c = col0 + wn * 64 + j * 16 + ln;
            if (c < N) {
#pragma unroll
                for (int t = 0; t < 4; ++t) {
                    const int r = row0 + wm * 64 + i * 16 + q * 4 + t;
                    const size_t o = zoff + (size_t)r * ldc + c;
                    const float v = acc[i][j][t];
                    if (MODE == 0)      ((f16*)Cg)[o] = (f16)v;
                    else if (MODE == 1) ((float*)Cg)[o] = v;
                    else                ((float*)Cg)[o] += v;
                }
            }
        }
    }
}

// ---------------------------------------------------------------------------
// fp64 MFMA layout probe. One wave. Determines the gfx950 lane<->matrix
// mapping of v_mfma_f64_16x16x4 empirically (m89 lesson: never trust an
// unverified MFMA layout).
//   probe A: a=lane, b=1  -> D[i][j] = sum_k l_A(i,k), reveals A variant + i(l,r)
//   probe B: a=1, b=lane  -> D[i][j] = sum_k l_B(k,j), reveals B variant + j(l,r)
// Variant "m/n in low 4 bits": value = 4*idx + 96 (== 0 mod 4)
// Variant "k in low 2 bits":   value = 16*idx + 6 (== 2 mod 4)  -- disjoint.
// tbl[l*12 + {0..3}] = mA,kA,nB,kB ; +{4..7} = i(l,r) ; +{8..11} = j(l,r)
// ---------------------------------------------------------------------------
__global__ void probe_f64_k(int* __restrict__ tbl) {
    int l = threadIdx.x & 63;
    f64x4 z = (f64x4){0.0, 0.0, 0.0, 0.0};
    f64x4 dA = __builtin_amdgcn_mfma_f64_16x16x4f64((double)l, 1.0, z, 0, 0, 0);
    f64x4 dB = __builtin_amdgcn_mfma_f64_16x16x4f64(1.0, (double)l, z, 0, 0, 0);
    int* t = tbl + l * 12;
    {
        int v = (int)dA[0];
        if ((v & 3) == 0) { t[0] = l & 15; t[1] = l >> 4; }
        else              { t[0] = l >> 2; t[1] = l & 3;  }
    }
    {
        int v = (int)dB[0];
        if ((v & 3) == 0) { t[2] = l & 15; t[3] = l >> 4; }
        else              { t[2] = l >> 2; t[3] = l & 3;  }
    }
#pragma unroll
    for (int r = 0; r < 4; ++r) {
        int vA = (int)dA[r];
        t[4 + r] = ((vA & 3) == 0) ? (vA - 96) / 4 : (vA - 6) / 16;
        int vB = (int)dB[r];
        t[8 + r] = ((vB & 3) == 0) ? (vB - 96) / 4 : (vB - 6) / 16;
    }
}

// ---------------------------------------------------------------------------
// fp64 MFMA GEMM (pool-argmax-critical path). TILE 64x64, BK 16, 256 thr.
// Lane->matrix mapping supplied by the probe table (loop-invariant address
// bases: zero hot-loop overhead). Wave w owns rows 16w..16w+15, 4 n-tiles.
// Register prefetch of next k-tile. A may be fp32 (converted on load) or
// fp64. M%64==0, K%16==0, N%4==0. Staging identical to the verified R7 core.
// ---------------------------------------------------------------------------
#define LDD 66

__device__ inline void loadA4(const float* p, double* d) {
    float4 v = *(const float4*)p;
    d[0] = v.x; d[1] = v.y; d[2] = v.z; d[3] = v.w;
}
__device__ inline void loadA4(const double* p, double* d) {
    double2 v0 = *(const double2*)p, v1 = *(const double2*)(p + 2);
    d[0] = v0.x; d[1] = v0.y; d[2] = v1.x; d[3] = v1.y;
}

template <typename TA>
__global__ __launch_bounds__(256) void gemm_f64(
    const TA* __restrict__ A, const double* __restrict__ Bg, double* __restrict__ Cg,
    const int* __restrict__ tbl,
    int M, int K, int N, long long sB, long long sC, int accum)
{
    const double* B = Bg + (size_t)blockIdx.z * sB;
    double*       C = Cg + (size_t)blockIdx.z * sC;

    __shared__ double As[16][LDD];   // As[k][m]
    __shared__ double Bs[16][LDD];   // Bs[k][n]

    const int tid  = threadIdx.x;
    const int lane = tid & 63;
    const int wv   = tid >> 6;       // wave 0..3 -> rows 16*wv..16*wv+15
    const int m0   = wv << 4;

    // probe-measured per-lane mapping
    const int* tl = tbl + lane * 12;
    const int mA = tl[0], kA = tl[1], nB = tl[2], kB = tl[3];
    int iT[4], jT[4];
#pragma unroll
    for (int r = 0; r < 4; ++r) { iT[r] = tl[4 + r]; jT[r] = tl[8 + r]; }

    const int row0 = blockIdx.y * 64;
    const int col0 = blockIdx.x * 64;

    const int ra = tid >> 2;          // A-stage row 0..63
    const int ka = (tid & 3) << 2;    // A-stage k 0,4,8,12
    const int kb = tid >> 4;          // B-stage k 0..15
    const int cb = (tid & 15) << 2;   // B-stage col 0..60

    const TA* Arow = A + (size_t)(row0 + ra) * K + ka;
    const int cbase = col0 + cb;

    f64x4 acc[4];
#pragma unroll
    for (int j = 0; j < 4; ++j) acc[j] = (f64x4){0.0, 0.0, 0.0, 0.0};

    // prologue loads (k0 = 0)
    double av[4];
    double2 bv0 = {0.0, 0.0}, bv1 = {0.0, 0.0};
    loadA4(Arow, av);
    if (cbase < N) {
        bv0 = *(const double2*)(B + (size_t)kb * N + cbase);
        bv1 = *(const double2*)(B + (size_t)kb * N + cbase + 2);
    }

    for (int k0 = 0; k0 < K; k0 += 16) {
        __syncthreads();
        As[ka + 0][ra] = av[0]; As[ka + 1][ra] = av[1];
        As[ka + 2][ra] = av[2]; As[ka + 3][ra] = av[3];
        *(double2*)&Bs[kb][cb]     = bv0;
        *(double2*)&Bs[kb][cb + 2] = bv1;
        __syncthreads();

        // prefetch k0+16 (overlaps MFMA block)
        if (k0 + 16 < K) {
            loadA4(Arow + k0 + 16, av);
            if (cbase < N) {
                bv0 = *(const double2*)(B + (size_t)(k0 + 16 + kb) * N + cbase);
                bv1 = *(const double2*)(B + (size_t)(k0 + 16 + kb) * N + cbase + 2);
            }
        }

#pragma unroll
        for (int kq = 0; kq < 4; ++kq) {
            const double a = As[(kq << 2) + kA][m0 + mA];
#pragma unroll
            for (int j = 0; j < 4; ++j) {
                const double b = Bs[(kq << 2) + kB][(j << 4) + nB];
                acc[j] = __builtin_amdgcn_mfma_f64_16x16x4f64(a, b, acc[j], 0, 0, 0);
            }
        }
    }

#pragma unroll
    for (int j = 0; j < 4; ++j) {
#pragma unroll
        for (int r = 0; r < 4; ++r) {
            const int c = col0 + (j << 4) + jT[r];
            if (c < N) {
                const int rr = row0 + m0 + iT[r];
                double* p = C + (size_t)rr * N + c;
                double v = acc[j][r];
                if (accum) v += *p;
                *p = v;
            }
        }
    }
}

// ---------------------------------------------------------------------------
// Aux kernels. Activation layout: [g=4][node][b=8][C].
// ---------------------------------------------------------------------------
__global__ void zero_k(float* __restrict__ p, int n) {
    int i = blockIdx.x * blockDim.x + threadIdx.x;
    if (i < n) p[i] = 0.f;
}

__global__ void cast16_k(const float* __restrict__ s, f16* __restrict__ d, int n) {
    int i = blockIdx.x * blockDim.x + threadIdx.x;
    if (i < n) d[i] = (f16)s[i];
}

// x [32][3072][32] fp32 -> XT64 [g][n][bi][32] fp64
__global__ void regroup_in64_k(const float* __restrict__ x, double* __restrict__ XT, int total) {
    int i = blockIdx.x * blockDim.x + threadIdx.x;
    if (i >= total) return;
    int c = i & 31;
    int t = i >> 5;
    int n = t % 3072;
    int b = t / 3072;
    XT[((((size_t)(b >> 3) * 3072 + n) << 3) + (b & 7)) * 32 + c] = (double)x[i];
}

// fp16 combine: wa=w0-w2, wb=w1, wc=2*w2
__global__ void cheb_combine16_k(const float* __restrict__ w, f16* __restrict__ wa,
                                 f16* __restrict__ wb, f16* __restrict__ wc, int n) {
    int i = blockIdx.x * blockDim.x + threadIdx.x;
    if (i >= n) return;
    float w0 = w[i], w1 = w[n + i], w2 = w[2 * n + i];
    wa[i] = (f16)(w0 - w2); wb[i] = (f16)w1; wc[i] = (f16)(2.f * w2);
}
// fp64 combine (encoder)
__global__ void cheb_combine64_k(const float* __restrict__ w, double* __restrict__ wa,
                                 double* __restrict__ wb, double* __restrict__ wc, int n) {
    int i = blockIdx.x * blockDim.x + threadIdx.x;
    if (i >= n) return;
    double w0 = w[i], w1 = w[n + i], w2 = w[2 * n + i];
    wa[i] = w0 - w2; wb[i] = w1; wc[i] = 2.0 * w2;
}

__global__ void transpose_w16_k(const float* __restrict__ w, f16* __restrict__ wt, int R, int Ccol) {
    int i = blockIdx.x * blockDim.x + threadIdx.x;
    if (i >= R * Ccol) return;
    int r = i / Ccol, c = i - r * Ccol;
    wt[(size_t)c * R + r] = (f16)w[i];
}
__global__ void transpose_w64_k(const float* __restrict__ w, double* __restrict__ wt, int R, int Ccol) {
    int i = blockIdx.x * blockDim.x + threadIdx.x;
    if (i >= R * Ccol) return;
    int r = i / Ccol, c = i - r * Ccol;
    wt[(size_t)c * R + r] = (double)w[i];
}

// fp32 BN (stats; apply in-place + optional f16 mirror)
__global__ void bn_reduce_k(const float* __restrict__ X, float* __restrict__ stats,
                            int rows, int ld, int off) {
    int c = threadIdx.x;
    float s = 0.f, s2 = 0.f;
    for (int r = blockIdx.x; r < rows; r += gridDim.x) {
        float v = X[(size_t)r * ld + off + c];
        s += v; s2 += v * v;
    }
    atomicAdd(&stats[c], s);
    atomicAdd(&stats[256 + c], s2);
}
__global__ void bn_apply_k(float* X, const float* __restrict__ stats,
                           const float* __restrict__ g, const float* __restrict__ be,
                           const float* rbias, f16* mirror,
                           int total, int C, float invN, int ld, int off) {
    int i = blockIdx.x * blockDim.x + threadIdx.x;
    if (i >= total) return;
    int c = i % C;
    int row = i / C;
    size_t a = (size_t)row * ld + off + c;
    float mu = stats[c] * invN;
    float var = stats[256 + c] * invN - mu * mu;
    float sc = g[c] * rsqrtf(var + 1e-5f);
    float v = (X[a] - mu) * sc + be[c];
    v = fmaxf(v, 0.f);
    if (rbias) v += rbias[c];
    X[a] = v;
    if (mirror) mirror[a] = (f16)v;
}

// fp64 BN (encoder)
__global__ void bn_reduce64_k(const double* __restrict__ X, double* __restrict__ stats,
                              int rows, int ld) {
    int c = threadIdx.x;
    double s = 0.0, s2 = 0.0;
    for (int r = blockIdx.x; r < rows; r += gridDim.x) {
        double v = X[(size_t)r * ld + c];
        s += v; s2 += v * v;
    }
    atomicAdd(&stats[c], s);
    atomicAdd(&stats[256 + c], s2);
}
__global__ void bn_apply64_k(double* X, const double* __restrict__ stats,
                             const float* __restrict__ g, const float* __restrict__ be,
                             const float* rbias, int total, int C, double invN) {
    int i = blockIdx.x * blockDim.x + threadIdx.x;
    if (i >= total) return;
    int c = i % C;
    double mu = stats[c] * invN;
    double var = stats[256 + c] * invN - mu * mu;
    double sc = (double)g[c] / sqrt(var + 1e-5);
    double v = (X[i] - mu) * sc + (double)be[c];
    v = v > 0.0 ? v : 0.0;
    if (rbias) v += (double)rbias[c];
    X[i] = v;
}

// fp64 e1 [row][128] -> CATh high half (f16, ld 256, off 128)
__global__ void cast_e1_k(const double* __restrict__ E1, f16* __restrict__ cat, int total) {
    int i = blockIdx.x * blockDim.x + threadIdx.x;
    if (i >= total) return;
    int c = i & 127;
    int row = i >> 7;
    cat[(size_t)row * 256 + 128 + c] = (f16)E1[i];
}

// pool 4 consecutive nodes of fp64 e1 -> Ph f16 [g][q][b][128], IDX node index
__global__ void pool4_64_k(const double* __restrict__ e1, f16* __restrict__ p,
                           int* __restrict__ idx, int total) {
    int i = blockIdx.x * blockDim.x + threadIdx.x;
    if (i >= total) return;
    int c = i & 127;
    int t = i >> 7;
    int b = t & 7;
    t >>= 3;
    int q = t % 768;
    int g = t / 768;
    size_t base = ((((size_t)g * 3072 + 4 * q) << 3) + b) * 128 + c;
    double best = e1[base];
    int bj = 0;
#pragma unroll
    for (int j = 1; j < 4; ++j) {
        double v = e1[base + (size_t)j * 1024];
        if (v > best) { best = v; bj = j; }   // strict >: first occurrence (jnp.argmax)
    }
    p[i] = (f16)best;
    idx[i] = 4 * q + bj;
}

// scatter e2 (fp32) into CATh low half (f16)
__global__ void unpool_cat_k(const float* __restrict__ e2, const int* __restrict__ idx,
                             f16* __restrict__ cat, int total) {
    int i = blockIdx.x * blockDim.x + threadIdx.x;
    if (i >= total) return;
    int c = i & 127;
    int t = i >> 7;
    int b = t & 7;
    t >>= 3;
    int q = t % 768;
    int g = t / 768;
    f16 val = (f16)e2[i];
    int id = idx[i];
    size_t base = ((((size_t)g * 3072 + 4 * q) << 3) + b) * 256 + c;
#pragma unroll
    for (int j = 0; j < 4; ++j)
        cat[base + (size_t)j * 2048] = (4 * q + j == id) ? val : (f16)0.f;
}

// O [g][n][bi][8] fp32 -> out [B][N][8], + bias
__global__ void transpose_out_k(const float* __restrict__ O, const float* __restrict__ bias,
                                float* __restrict__ out, int total) {
    int i = blockIdx.x * blockDim.x + threadIdx.x;
    if (i >= total) return;
    int c = i & 7;
    int t = i >> 3;
    int n = t % 3072;
    int b = t / 3072;
    out[i] = O[((((size_t)(b >> 3) * 3072 + n) << 3) + (b & 7)) * 8 + c] + bias[c];
}

// ---------------------------------------------------------------------------
extern "C" void kernel_launch(void* const* d_in, const int* in_sizes, int n_in,
                              void* d_out, int out_size, void* d_ws, size_t ws_size,
                              hipStream_t stream)
{
    (void)in_sizes; (void)n_in; (void)out_size; (void)ws_size;

    const float* x    = (const float*)d_in[0];
    const float* L0   = (const float*)d_in[1];
    const float* L1   = (const float*)d_in[2];
    const float* w11  = (const float*)d_in[3];
    const float* g11  = (const float*)d_in[5];
    const float* be11 = (const float*)d_in[6];
    const float* w13  = (const float*)d_in[7];
    const float* g13  = (const float*)d_in[9];
    const float* be13 = (const float*)d_in[10];
    const float* wr1  = (const float*)d_in[11];
    const float* br1  = (const float*)d_in[12];
    const float* w21  = (const float*)d_in[13];
    const float* g21  = (const float*)d_in[15];
    const float* be21 = (const float*)d_in[16];
    const float* w23  = (const float*)d_in[17];
    const float* g23  = (const float*)d_in[19];
    const float* be23 = (const float*)d_in[20];
    const float* wr2  = (const float*)d_in[21];
    const float* br2  = (const float*)d_in[22];
    const float* uw11 = (const float*)d_in[23];
    const float* ug11 = (const float*)d_in[25];
    const float* ube11= (const float*)d_in[26];
    const float* uw12 = (const float*)d_in[27];
    const float* ug12 = (const float*)d_in[29];
    const float* ube12= (const float*)d_in[30];
    const float* uwr1 = (const float*)d_in[31];
    const float* ubr1 = (const float*)d_in[32];
    const float* uw13 = (const float*)d_in[33];
    const float* ub13 = (const float*)d_in[34];
    float* out = (float*)d_out;

    float* ws = (float*)d_ws;
    size_t off = 0;
    auto alloc = [&](size_t n) { float* p = ws + off; off += (n + 63) & ~(size_t)63; return p; };

    // ---- regions (floats). Total ~224 MiB. ----
    float* R1 = alloc(12582912);   // CATh f16[25165824] | p1: H1 dbl[6291456]
    float* R2 = alloc(25165824);   // D1 fp32 + H64 fp32 + T1h/T2h f16 | p1: E1 dbl[12582912]
    float* R3 = alloc(6291456);    // p1: XT64 dbl[3145728] | p2: H2h f16 then D1h f16
    float* R4 = alloc(6291456);    // p1: T1d dbl[3145728] | p2: Ph f16 + H64h f16
    int*  IDX = (int*)alloc(3145728);  // p1 (with L0f): T2d dbl[3145728]
    float* L0f = alloc(4718592);   // p2: L0h f16[9437184]
    float* L1f = alloc(294912);    // p2: L1h f16[589824]
    float* ST  = alloc(1536);      // fp32 stats [0..512), fp64 stats [512..1536)
    int*  TBL  = (int*)alloc(768); // f64-MFMA layout table (64 lanes x 12 ints)

    // f16 weights
    f16* wa21h = (f16*)alloc(12288); f16* wb21h = (f16*)alloc(12288); f16* wc21h = (f16*)alloc(12288);
    f16* wa23h = (f16*)alloc(12288); f16* wb23h = (f16*)alloc(12288); f16* wc23h = (f16*)alloc(12288);
    f16* wau11h = (f16*)alloc(16384); f16* wbu11h = (f16*)alloc(16384); f16* wcu11h = (f16*)alloc(16384);
    f16* wau12h = (f16*)alloc(4096);  f16* wbu12h = (f16*)alloc(4096);  f16* wcu12h = (f16*)alloc(4096);
    f16* wau13h = (f16*)alloc(256);   f16* wbu13h = (f16*)alloc(256);   f16* wcu13h = (f16*)alloc(256);
    f16* wr2Th  = (f16*)alloc(8192);
    f16* uwr1Th = (f16*)alloc(8192);

    // fp64 weights (encoder)
    double* wa11_64 = (double*)alloc(4096);
    double* wb11_64 = (double*)alloc(4096);
    double* wc11_64 = (double*)alloc(4096);
    double* wa13_64 = (double*)alloc(16384);
    double* wb13_64 = (double*)alloc(16384);
    double* wc13_64 = (double*)alloc(16384);
    double* wr1T_64 = (double*)alloc(8192);

    // ---- aliases ----
    f16*    CATh = (f16*)R1;
    double* H1   = (double*)R1;
    float*  D1   = R2;                       // [g][n][b][128] fp32
    float*  H2   = R2;                       // [g][q][b][192] fp32
    float*  Y3   = R2 + 4718592;             // [g][q][b][128] fp32
    float*  O    = R2;                       // final [g][n][b][8] fp32
    float*  H64  = R2 + 12582912;            // [g][n][b][64] fp32
    f16*    T1h  = (f16*)(R2 + 18874368);    // f16[6291456]
    f16*    T2h  = (f16*)(R2 + 22020096);    // f16[6291456]
    double* E1   = (double*)R2;              // dbl[12582912] spans R2
    double* XT64 = (double*)R3;
    f16*    H2h  = (f16*)R3;                 // early phase-2
    f16*    D1h  = (f16*)R3;                 // late phase-2 (H2h dead)
    double* T1d  = (double*)R4;              // dbl[3145728]
    double* T2d  = (double*)IDX;             // dbl[3145728] spanning IDX + L0f front half
    f16*    Ph   = (f16*)R4;                 // f16[3145728] (phase 2)
    f16*    H64h = (f16*)(R4 + 1572864);     // f16[6291456] (phase 2)
    f16*    L0h  = (f16*)L0f;
    f16*    L1h  = (f16*)L1f;
    double* ST64 = (double*)(ST + 512);

    auto gh = [&](int mode, const f16* A, const f16* B, void* C, int M, int K, int N,
                  int ldc, long long sB, long long sC, int z) {
        dim3 grid((N + 127) / 128, M / 128, z);
        if (mode == 0)      gemm_h<0><<<grid, 256, 0, stream>>>(A, B, C, M, K, N, ldc, sB, sC);
        else if (mode == 1) gemm_h<1><<<grid, 256, 0, stream>>>(A, B, C, M, K, N, ldc, sB, sC);
        else                gemm_h<2><<<grid, 256, 0, stream>>>(A, B, C, M, K, N, ldc, sB, sC);
    };
    auto gemm64f = [&](const float* A, const double* B, double* C, int M, int K, int N,
                       long long sB, long long sC, int z, int accum) {
        dim3 grid((N + 63) / 64, M / 64, z);
        gemm_f64<float><<<grid, 256, 0, stream>>>(A, B, C, TBL, M, K, N, sB, sC, accum);
    };
    auto gemm64d = [&](const double* A, const double* B, double* C, int M, int K, int N, int accum) {
        dim3 grid((N + 63) / 64, M / 64);
        gemm_f64<double><<<grid, 256, 0, stream>>>(A, B, C, TBL, M, K, N, 0, 0, accum);
    };
    auto bn = [&](float* X, int rows, int C, int ld, int offc,
                  const float* gp, const float* bep, const float* rbias, f16* mirror) {
        zero_k<<<2, 256, 0, stream>>>(ST, 512);
        bn_reduce_k<<<384, C, 0, stream>>>(X, ST, rows, ld, offc);
        int total = rows * C;
        bn_apply_k<<<(total + 255) / 256, 256, 0, stream>>>(
            X, ST, gp, bep, rbias, mirror, total, C, 1.f / (float)rows, ld, offc);
    };
    auto bn64 = [&](double* X, int rows, int C,
                    const float* gp, const float* bep, const float* rbias) {
        zero_k<<<4, 256, 0, stream>>>(ST + 512, 1024);
        bn_reduce64_k<<<384, C, 0, stream>>>(X, ST64, rows, C);
        int total = rows * C;
        bn_apply64_k<<<(total + 255) / 256, 256, 0, stream>>>(
            X, ST64, gp, bep, rbias, total, C, 1.0 / (double)rows);
    };
    auto comb16 = [&](const float* w, f16* a, f16* b, f16* c, int n) {
        cheb_combine16_k<<<(n + 255) / 256, 256, 0, stream>>>(w, a, b, c, n);
    };

    // ---- f64-MFMA layout probe (must precede all gemm_f64 launches) ----
    probe_f64_k<<<1, 64, 0, stream>>>(TBL);

    // ---- fp64 weight prep + input regroup ----
    cheb_combine64_k<<<8, 256, 0, stream>>>(w11, wa11_64, wb11_64, wc11_64, 2048);
    cheb_combine64_k<<<32, 256, 0, stream>>>(w13, wa13_64, wb13_64, wc13_64, 8192);
    transpose_w64_k<<<16, 256, 0, stream>>>(wr1, wr1T_64, 128, 32);
    regroup_in64_k<<<12288, 256, 0, stream>>>(x, XT64, 3145728);

    // ==== PHASE 1 (fp64 MFMA): encoder to e1, exact argmax ====
    // conv1: 32 -> 64, z=4 batched (T1d/T2d = [4][3072][256] dbl)
    gemm64f(L0, XT64, T1d, 3072, 3072, 256, 786432, 786432, 4, 0);
    gemm64f(L0, T1d, T2d, 3072, 3072, 256, 786432, 786432, 4, 0);
    gemm64d(XT64, wa11_64, H1, 98304, 32, 64, 0);
    gemm64d(T1d,  wb11_64, H1, 98304, 32, 64, 1);
    gemm64d(T2d,  wc11_64, H1, 98304, 32, 64, 1);
    bn64(H1, 98304, 64, g11, be11, nullptr);                 // h1

    // conv2: 64 -> 128, two z=2 halves (T1d/T2d = [2][3072][512] dbl)
    for (int h = 0; h < 2; ++h) {
        const double* Hh = H1 + (size_t)h * 3145728;
        double*       Eh = E1 + (size_t)h * 6291456;
        gemm64f(L0, Hh, T1d, 3072, 3072, 512, 1572864, 1572864, 2, 0);
        gemm64f(L0, T1d, T2d, 3072, 3072, 512, 1572864, 1572864, 2, 0);
        gemm64d(Hh,  wa13_64, Eh, 49152, 64, 128, 0);
        gemm64d(T1d, wb13_64, Eh, 49152, 64, 128, 1);
        gemm64d(T2d, wc13_64, Eh, 49152, 64, 128, 1);
    }
    bn64(E1, 98304, 128, g13, be13, br1);
    gemm64d(XT64, wr1T_64, E1, 98304, 32, 128, 1);           // e1 (fp64)

    // ---- f16 weight prep (delayed: L0f/IDX regions were phase-1 scratch) ----
    comb16(w21,  wa21h,  wb21h,  wc21h,  24576);
    comb16(w23,  wa23h,  wb23h,  wc23h,  24576);
    comb16(uw11, wau11h, wbu11h, wcu11h, 32768);
    comb16(uw12, wau12h, wbu12h, wcu12h, 8192);
    comb16(uw13, wau13h, wbu13h, wcu13h, 512);
    transpose_w16_k<<<64, 256, 0, stream>>>(wr2, wr2Th, 128, 128);
    transpose_w16_k<<<64, 256, 0, stream>>>(uwr1, uwr1Th, 64, 256);
    cast16_k<<<36864, 256, 0, stream>>>(L0, L0h, 9437184);
    cast16_k<<<2304, 256, 0, stream>>>(L1, L1h, 589824);

    // transition: pool on fp64; CATh high = f16(e1)
    pool4_64_k<<<12288, 256, 0, stream>>>(E1, Ph, IDX, 3145728);
    cast_e1_k<<<49152, 256, 0, stream>>>(E1, CATh, 12582912);
    // E1 / XT64 / H1 / T1d / T2d dead from here.

    // ==== PHASE 2 (fp16 MFMA) ====
    // L2 conv1: 128 -> 192
    gh(0, L1h, Ph, T1h, 768, 768, 1024, 1024, 786432, 786432, 4);
    gh(0, L1h, T1h, T2h, 768, 768, 1024, 1024, 786432, 786432, 4);
    gh(1, Ph,  wa21h, H2, 24576, 128, 192, 192, 0, 0, 1);
    gh(2, T1h, wb21h, H2, 24576, 128, 192, 192, 0, 0, 1);
    gh(2, T2h, wc21h, H2, 24576, 128, 192, 192, 0, 0, 1);
    bn(H2, 24576, 192, 192, 0, g21, be21, nullptr, H2h);     // h2 (+f16 mirror)

    // L2 conv2: 192 -> 128, + residual -> e2 (Y3)
    gh(0, L1h, H2h, T1h, 768, 768, 1536, 1536, 1179648, 1179648, 4);
    gh(0, L1h, T1h, T2h, 768, 768, 1536, 1536, 1179648, 1179648, 4);
    gh(1, H2h, wa23h, Y3, 24576, 192, 128, 128, 0, 0, 1);
    gh(2, T1h, wb23h, Y3, 24576, 192, 128, 128, 0, 0, 1);
    gh(2, T2h, wc23h, Y3, 24576, 192, 128, 128, 0, 0, 1);
    bn(Y3, 24576, 128, 128, 0, g23, be23, br2, nullptr);
    gh(2, Ph, wr2Th, Y3, 24576, 128, 128, 128, 0, 0, 1);     // e2

    // unpool into CATh low (f16)
    unpool_cat_k<<<12288, 256, 0, stream>>>(Y3, IDX, CATh, 3145728);

    // dec conv1: 256 -> 128 (per group)
    for (int g = 0; g < 4; ++g) {
        const f16* Bg = CATh + (size_t)g * 6291456;
        float* Dg = D1 + (size_t)g * 3145728;
        gh(0, L0h, Bg, T1h, 3072, 3072, 2048, 2048, 0, 0, 1);
        gh(0, L0h, T1h, T2h, 3072, 3072, 2048, 2048, 0, 0, 1);
        gh(1, Bg,  wau11h, Dg, 24576, 256, 128, 128, 0, 0, 1);
        gh(2, T1h, wbu11h, Dg, 24576, 256, 128, 128, 0, 0, 1);
        gh(2, T2h, wcu11h, Dg, 24576, 256, 128, 128, 0, 0, 1);
    }
    bn(D1, 98304, 128, 128, 0, ug11, ube11, nullptr, D1h);   // d1 (+f16 mirror)

    // dec conv2: 128 -> 64, + residual from cat
    for (int g = 0; g < 4; ++g) {
        const f16* Bg = D1h + (size_t)g * 3145728;           // 128-ch group stride
        float* Dg = H64 + (size_t)g * 1572864;
        gh(0, L0h, Bg, T1h, 3072, 3072, 1024, 1024, 0, 0, 1);
        gh(0, L0h, T1h, T2h, 3072, 3072, 1024, 1024, 0, 0, 1);
        gh(1, Bg,  wau12h, Dg, 24576, 128, 64, 64, 0, 0, 1);
        gh(2, T1h, wbu12h, Dg, 24576, 128, 64, 64, 0, 0, 1);
        gh(2, T2h, wcu12h, Dg, 24576, 128, 64, 64, 0, 0, 1);
    }
    bn(H64, 98304, 64, 64, 0, ug12, ube12, ubr1, nullptr);
    gh(2, CATh, uwr1Th, H64, 98304, 256, 64, 64, 0, 0, 1);   // d2 = bn + residual
    cast16_k<<<24576, 256, 0, stream>>>(H64, H64h, 6291456); // d2 f16 mirror

    // final conv: 64 -> 8
    gh(0, L0h, H64h, T1h, 3072, 3072, 512, 512, 1572864, 1572864, 4);
    gh(0, L0h, T1h, T2h, 3072, 3072, 512, 512, 1572864, 1572864, 4);
    gh(1, H64h, wau13h, O, 98304, 64, 8, 8, 0, 0, 1);
    gh(2, T1h,  wbu13h, O, 98304, 64, 8, 8, 0, 0, 1);
    gh(2, T2h,  wcu13h, O, 98304, 64, 8, 8, 0, 0, 1);

    transpose_out_k<<<3072, 256, 0, stream>>>(O, ub13, out, 786432);
}